// Round 2
// baseline (1146.570 us; speedup 1.0000x reference)
//
#include <hip/hip_runtime.h>
#include <stdint.h>

// B=2048, S=32, D=1024, H=16, DK=64. d_in/d_out are FLOAT32; internal bf16.
// Pipeline: transpose_w -> ln -> 8x( gemm<QKV chunk> -> attn chunk ) -> gemm<OUT>.
// ws (ushort elems): WcatT[3072*1024] | WoT[1024*1024] | xn&ctx[65536*1024] | QKVchunk[3*8192*1024]
// total ~184 MB.

typedef __attribute__((ext_vector_type(8))) short bf16x8;
typedef __attribute__((ext_vector_type(4))) float f32x4;
typedef __attribute__((ext_vector_type(16))) float f32x16;

__device__ __forceinline__ float bf2f(unsigned short u) {
    return __uint_as_float(((unsigned)u) << 16);
}
__device__ __forceinline__ unsigned short f2bf(float f) {
    unsigned u = __float_as_uint(f);
    u += 0x7FFFu + ((u >> 16) & 1u);
    return (unsigned short)(u >> 16);
}
__device__ __forceinline__ uint4 pack8(const float* f) {
    uint4 u;
    u.x = (unsigned)f2bf(f[0]) | ((unsigned)f2bf(f[1]) << 16);
    u.y = (unsigned)f2bf(f[2]) | ((unsigned)f2bf(f[3]) << 16);
    u.z = (unsigned)f2bf(f[4]) | ((unsigned)f2bf(f[5]) << 16);
    u.w = (unsigned)f2bf(f[6]) | ((unsigned)f2bf(f[7]) << 16);
    return u;
}

typedef __attribute__((address_space(3))) unsigned lds_u32;
typedef const __attribute__((address_space(1))) unsigned glb_u32;
__device__ __forceinline__ void gld16(const void* g, void* l) {
    __builtin_amdgcn_global_load_lds((glb_u32*)g, (lds_u32*)l, 16, 0, 0);
}

// ---------------------------------------------------------------- transpose
// WcatT[3072][1024] = [wq^T; wk^T; wv^T] (bf16), WoT[1024][1024] = wo^T (bf16).
__global__ __launch_bounds__(256) void transpose_w(
    const float* __restrict__ wq, const float* __restrict__ wk,
    const float* __restrict__ wv, const float* __restrict__ wo,
    unsigned short* __restrict__ wcatT, unsigned short* __restrict__ woT)
{
    __shared__ unsigned short T[64 * 72];
    int bid = blockIdx.x;
    int p = bid >> 8;          // 0..3
    int t = bid & 255;
    int k0 = (t >> 4) * 64, n0 = (t & 15) * 64;
    const float* src = (p == 0) ? wq : (p == 1) ? wk : (p == 2) ? wv : wo;
    unsigned short* dst = (p < 3) ? (wcatT + (size_t)p * 1048576) : woT;
    int tid = threadIdx.x;
#pragma unroll
    for (int it = 0; it < 2; it++) {
        int flat = it * 2048 + tid * 8;
        int r = flat >> 6, c = flat & 63;
        const float* s4 = src + (size_t)(k0 + r) * 1024 + n0 + c;
        float4 u0 = *(const float4*)s4;
        float4 u1 = *(const float4*)(s4 + 4);
        float f[8] = {u0.x, u0.y, u0.z, u0.w, u1.x, u1.y, u1.z, u1.w};
        *(uint4*)&T[r * 72 + c] = pack8(f);
    }
    __syncthreads();
#pragma unroll
    for (int it = 0; it < 2; it++) {
        int flat = it * 2048 + tid * 8;
        int rn = flat >> 6, ck = flat & 63;
        unsigned short v[8];
#pragma unroll
        for (int j = 0; j < 8; j++) v[j] = T[(ck + j) * 72 + rn];
        uint4 u;
        u.x = (unsigned)v[0] | ((unsigned)v[1] << 16);
        u.y = (unsigned)v[2] | ((unsigned)v[3] << 16);
        u.z = (unsigned)v[4] | ((unsigned)v[5] << 16);
        u.w = (unsigned)v[6] | ((unsigned)v[7] << 16);
        *(uint4*)(dst + (size_t)(n0 + rn) * 1024 + k0 + ck) = u;
    }
}

// ---------------------------------------------------------------- layernorm
// f32 in -> bf16 out. One wave per row of 1024.
__global__ __launch_bounds__(256) void ln_kernel(
    const float* __restrict__ x, const float* __restrict__ gg,
    const float* __restrict__ bb, unsigned short* __restrict__ xn)
{
    int l = threadIdx.x & 63;
    size_t row = (size_t)blockIdx.x * 4 + (threadIdx.x >> 6);
    const float* xr = x + row * 1024;
    float f0[8], f1[8];
    *(float4*)&f0[0] = *(const float4*)(xr + l * 8);
    *(float4*)&f0[4] = *(const float4*)(xr + l * 8 + 4);
    *(float4*)&f1[0] = *(const float4*)(xr + 512 + l * 8);
    *(float4*)&f1[4] = *(const float4*)(xr + 512 + l * 8 + 4);
    float s = 0.f, s2 = 0.f;
#pragma unroll
    for (int j = 0; j < 8; j++) { s += f0[j] + f1[j]; s2 += f0[j] * f0[j] + f1[j] * f1[j]; }
#pragma unroll
    for (int m = 1; m < 64; m <<= 1) { s += __shfl_xor(s, m); s2 += __shfl_xor(s2, m); }
    float mu = s * (1.f / 1024.f);
    float var = s2 * (1.f / 1024.f) - mu * mu;
    float rs = rsqrtf(var + 1e-5f);
    float fg0[8], fg1[8], fb0[8], fb1[8];
    *(float4*)&fg0[0] = *(const float4*)(gg + l * 8);
    *(float4*)&fg0[4] = *(const float4*)(gg + l * 8 + 4);
    *(float4*)&fg1[0] = *(const float4*)(gg + 512 + l * 8);
    *(float4*)&fg1[4] = *(const float4*)(gg + 512 + l * 8 + 4);
    *(float4*)&fb0[0] = *(const float4*)(bb + l * 8);
    *(float4*)&fb0[4] = *(const float4*)(bb + l * 8 + 4);
    *(float4*)&fb1[0] = *(const float4*)(bb + 512 + l * 8);
    *(float4*)&fb1[4] = *(const float4*)(bb + 512 + l * 8 + 4);
    float o0[8], o1[8];
#pragma unroll
    for (int j = 0; j < 8; j++) {
        o0[j] = (f0[j] - mu) * rs * fg0[j] + fb0[j];
        o1[j] = (f1[j] - mu) * rs * fg1[j] + fb1[j];
    }
    *(uint4*)(xn + row * 1024 + l * 8) = pack8(o0);
    *(uint4*)(xn + row * 1024 + 512 + l * 8) = pack8(o1);
}

// ---------------------------------------------------------------- GEMM (m97 structure)
// C[M, N=nt*128] = A[M,1024](bf16) @ Bt[N,1024]^T(bf16), K=1024. BM=BN=128,
// BK=32, 4 waves (2x2), each wave 64x64 = 4x4 frags of mfma 16x16x32.
// MODE 0: out(bf16) = QKV chunk scatter [proj][b_local][h][s][dk] + bias_f32
//         (M = 8192 rows of one chunk)
// MODE 1: out(f32)[row*1024+col] = acc + bias_f32[col] + resid_f32[row*1024+col]
template <int MODE>
__global__ __launch_bounds__(256) void gemm_bt(
    const unsigned short* __restrict__ A, const unsigned short* __restrict__ Bt,
    const float* __restrict__ bz0, const float* __restrict__ bz1,
    const float* __restrict__ bz2, const float* __restrict__ resid,
    void* __restrict__ outv, int nt)
{
    __shared__ unsigned short sA[128 * 32];
    __shared__ unsigned short sB[128 * 32];
    int bid = blockIdx.x;
    int mt = bid / nt, ntile = bid % nt;
    int m0 = mt * 128, n0 = ntile * 128;
    int tid = threadIdx.x, l = tid & 63, w = tid >> 6;
    int wr = w >> 1, wc = w & 1;

    int chunk0 = w * 2, chunk1 = w * 2 + 1;
    int srow0 = chunk0 * 16 + (l >> 2), srow1 = chunk1 * 16 + (l >> 2);
    int scol = (l & 3) * 8;
    const unsigned short* Ar0 = A + (size_t)(m0 + srow0) * 1024 + scol;
    const unsigned short* Ar1 = A + (size_t)(m0 + srow1) * 1024 + scol;
    const unsigned short* Br0 = Bt + (size_t)(n0 + srow0) * 1024 + scol;
    const unsigned short* Br1 = Bt + (size_t)(n0 + srow1) * 1024 + scol;
    unsigned short* sA0 = sA + chunk0 * 512;
    unsigned short* sA1 = sA + chunk1 * 512;
    unsigned short* sB0 = sB + chunk0 * 512;
    unsigned short* sB1 = sB + chunk1 * 512;

    f32x4 acc[4][4];
#pragma unroll
    for (int i = 0; i < 4; i++)
#pragma unroll
        for (int j = 0; j < 4; j++)
#pragma unroll
            for (int v = 0; v < 4; v++) acc[i][j][v] = 0.f;

    int aoff = (wr * 64 + (l & 15)) * 32 + (l >> 4) * 8;
    int boff = (wc * 64 + (l & 15)) * 32 + (l >> 4) * 8;

    for (int kk = 0; kk < 1024; kk += 32) {
        __syncthreads();
        gld16(Ar0 + kk, sA0);
        gld16(Ar1 + kk, sA1);
        gld16(Br0 + kk, sB0);
        gld16(Br1 + kk, sB1);
        __syncthreads();
        bf16x8 aF[4], bF[4];
#pragma unroll
        for (int i = 0; i < 4; i++) aF[i] = *(const bf16x8*)(sA + aoff + i * 512);
#pragma unroll
        for (int j = 0; j < 4; j++) bF[j] = *(const bf16x8*)(sB + boff + j * 512);
#pragma unroll
        for (int i = 0; i < 4; i++)
#pragma unroll
            for (int j = 0; j < 4; j++)
                acc[i][j] = __builtin_amdgcn_mfma_f32_16x16x32_bf16(aF[i], bF[j], acc[i][j], 0, 0, 0);
    }

    if (MODE == 0) {
        unsigned short* out = (unsigned short*)outv;
        int p = n0 >> 10;  // block-uniform projection index (nt=24 -> N=3072)
        const float* bp = (p == 0) ? bz0 : (p == 1) ? bz1 : bz2;
        size_t pbase = (size_t)p * 8388608ull;  // 8192*1024 per projection
#pragma unroll
        for (int j = 0; j < 4; j++) {
            int colg = n0 + wc * 64 + j * 16 + (l & 15);
            int nn = colg & 1023;
            float bias = bp[nn];
            int hh = nn >> 6, dk = nn & 63;
#pragma unroll
            for (int i = 0; i < 4; i++)
#pragma unroll
                for (int v = 0; v < 4; v++) {
                    int rowg = m0 + wr * 64 + i * 16 + (l >> 4) * 4 + v;  // chunk-local
                    int b_ = rowg >> 5, s_ = rowg & 31;                    // local batch
                    out[pbase + ((size_t)((b_ * 16 + hh) * 32 + s_) << 6) + dk] =
                        f2bf(acc[i][j][v] + bias);
                }
        }
    } else {
        float* out = (float*)outv;
#pragma unroll
        for (int j = 0; j < 4; j++) {
            int colg = n0 + wc * 64 + j * 16 + (l & 15);
            float bias = bz0[colg];
#pragma unroll
            for (int i = 0; i < 4; i++)
#pragma unroll
                for (int v = 0; v < 4; v++) {
                    int rowg = m0 + wr * 64 + i * 16 + (l >> 4) * 4 + v;
                    size_t idx = (size_t)rowg * 1024 + colg;
                    out[idx] = acc[i][j][v] + bias + resid[idx];
                }
        }
    }
}

// ---------------------------------------------------------------- attention
// 1 wave per (b_local, h) within a 256-batch chunk.
// QKV chunk layout: [proj][b_local][h][s=32][dk=64] bf16, proj stride 8388608.
__global__ __launch_bounds__(64) void attn_kernel(
    const unsigned short* __restrict__ qkv, const float* __restrict__ rb,
    unsigned short* __restrict__ ctx)
{
    __shared__ float Vs[32 * 68];
    __shared__ float Ps[32 * 33];
    int l = threadIdx.x, col = l & 31, hi = l >> 5;
    int bh = blockIdx.x, h = bh & 15;
    size_t base = (size_t)bh << 11;  // *2048
    const unsigned short* Qb = qkv + base;
    const unsigned short* Kb = Qb + 8388608ull;
    const unsigned short* Vb = Kb + 8388608ull;

    // stage V -> LDS f32 [32][68]
#pragma unroll
    for (int i = 0; i < 4; i++) {
        int flat = i * 512 + l * 8;
        int s = flat >> 6, d = flat & 63;
        uint4 u = *(const uint4*)(Vb + flat);
        Vs[s * 68 + d + 0] = bf2f((unsigned short)(u.x & 0xFFFF));
        Vs[s * 68 + d + 1] = bf2f((unsigned short)(u.x >> 16));
        Vs[s * 68 + d + 2] = bf2f((unsigned short)(u.y & 0xFFFF));
        Vs[s * 68 + d + 3] = bf2f((unsigned short)(u.y >> 16));
        Vs[s * 68 + d + 4] = bf2f((unsigned short)(u.z & 0xFFFF));
        Vs[s * 68 + d + 5] = bf2f((unsigned short)(u.z >> 16));
        Vs[s * 68 + d + 6] = bf2f((unsigned short)(u.w & 0xFFFF));
        Vs[s * 68 + d + 7] = bf2f((unsigned short)(u.w >> 16));
    }

    // QK^T via mfma_32x32x16: A row = lane&31 (q), B col = lane&31 (k-index),
    // k_frag = (lane>>5)*8 + j; 4 MFMA steps cover DK=64.
    f32x16 acc;
#pragma unroll
    for (int i = 0; i < 16; i++) acc[i] = 0.f;
#pragma unroll
    for (int t = 0; t < 4; t++) {
        bf16x8 aQ = *(const bf16x8*)(Qb + col * 64 + t * 16 + hi * 8);
        bf16x8 bK = *(const bf16x8*)(Kb + col * 64 + t * 16 + hi * 8);
        acc = __builtin_amdgcn_mfma_f32_32x32x16_bf16(aQ, bK, acc, 0, 0, 0);
    }

    // scale + rel_bias + row softmax; C/D row = (r&3)+8*(r>>2)+4*hi, col = lane&31
    const float* rbh = rb + h * 1024;
#pragma unroll
    for (int r = 0; r < 16; r++) {
        int m = (r & 3) + 8 * (r >> 2) + 4 * hi;
        float v = acc[r] * 0.125f + rbh[m * 32 + col];
        float mx = v;
#pragma unroll
        for (int msk = 1; msk < 32; msk <<= 1) mx = fmaxf(mx, __shfl_xor(mx, msk));
        float e = __expf(v - mx);
        float sm = e;
#pragma unroll
        for (int msk = 1; msk < 32; msk <<= 1) sm += __shfl_xor(sm, msk);
        Ps[m * 33 + col] = e / sm;
    }
    __syncthreads();

    // PV: lane -> (q = l>>1, d-block of 32)
    int q = l >> 1, dblk = (l & 1) << 5;
    float o[32];
#pragma unroll
    for (int d = 0; d < 32; d++) o[d] = 0.f;
    for (int k = 0; k < 32; k++) {
        float pv = Ps[q * 33 + k];
#pragma unroll
        for (int j = 0; j < 8; j++) {
            float4 v4 = *(const float4*)&Vs[k * 68 + dblk + j * 4];
            o[j * 4 + 0] += pv * v4.x;
            o[j * 4 + 1] += pv * v4.y;
            o[j * 4 + 2] += pv * v4.z;
            o[j * 4 + 3] += pv * v4.w;
        }
    }
    // ctx row (chunk-local) = b_local*32 + q, col = h*64 + dblk .. +31  (bf16)
    size_t ob = ((size_t)(bh >> 4) * 32 + q) * 1024 + h * 64 + dblk;
#pragma unroll
    for (int j = 0; j < 4; j++) *(uint4*)(ctx + ob + j * 8) = pack8(&o[j * 8]);
}

// ---------------------------------------------------------------- launch
extern "C" void kernel_launch(void* const* d_in, const int* in_sizes, int n_in,
                              void* d_out, int out_size, void* d_ws, size_t ws_size,
                              hipStream_t stream)
{
    const float* x  = (const float*)d_in[0];
    const float* lg = (const float*)d_in[1];
    const float* lb = (const float*)d_in[2];
    const float* wq = (const float*)d_in[3];
    const float* bq = (const float*)d_in[4];
    const float* wk = (const float*)d_in[5];
    const float* bk = (const float*)d_in[6];
    const float* wv = (const float*)d_in[7];
    const float* bv = (const float*)d_in[8];
    const float* wo = (const float*)d_in[9];
    const float* bo = (const float*)d_in[10];
    const float* rb = (const float*)d_in[11];
    float* out = (float*)d_out;
    unsigned short* ws = (unsigned short*)d_ws;

    unsigned short* wcatT = ws;                        // 3072*1024
    unsigned short* woT   = wcatT + 3145728;           // 1024*1024
    unsigned short* xnctx = woT + 1048576;             // 65536*1024 (xn, then ctx in place)
    unsigned short* qkvc  = xnctx + 67108864ull;       // 3*8192*1024 (one chunk)

    transpose_w<<<dim3(1024), dim3(256), 0, stream>>>(wq, wk, wv, wo, wcatT, woT);
    ln_kernel<<<dim3(16384), dim3(256), 0, stream>>>(x, lg, lb, xnctx);

    // 8 chunks of 256 batches (8192 rows each)
    for (int c = 0; c < 8; c++) {
        const unsigned short* Ac = xnctx + (size_t)c * 8388608ull;
        unsigned short* ctxc = xnctx + (size_t)c * 8388608ull;
        gemm_bt<0><<<dim3(1536), dim3(256), 0, stream>>>(
            Ac, wcatT, bq, bk, bv, (const float*)nullptr, (void*)qkvc, 24);
        attn_kernel<<<dim3(4096), dim3(64), 0, stream>>>(qkvc, rb, ctxc);
    }

    gemm_bt<1><<<dim3(4096), dim3(256), 0, stream>>>(
        xnctx, woT, bo, bo, bo, x, (void*)out, 8);
}

// Round 3
// 1095.872 us; speedup vs baseline: 1.0463x; 1.0463x over previous
//
#include <hip/hip_runtime.h>
#include <stdint.h>

// B=2048, S=32, D=1024, H=16, DK=64. d_in/d_out are FLOAT32; internal bf16.
// Pipeline: transpose_w -> ln -> Nc x( gemm<QKV chunk> -> attn chunk ) -> gemm<OUT>.
// ws (ushort): WcatT[3072*1024] | WoT[1024*1024] | xn&ctx[65536*1024] | QKVchunk
// Adaptive: 4 chunks (244 MB ws) if ws_size permits, else 8 chunks (184 MB).

typedef __attribute__((ext_vector_type(8))) short bf16x8;
typedef __attribute__((ext_vector_type(4))) float f32x4;
typedef __attribute__((ext_vector_type(16))) float f32x16;

__device__ __forceinline__ float bf2f(unsigned short u) {
    return __uint_as_float(((unsigned)u) << 16);
}
__device__ __forceinline__ unsigned short f2bf(float f) {
    unsigned u = __float_as_uint(f);
    u += 0x7FFFu + ((u >> 16) & 1u);
    return (unsigned short)(u >> 16);
}
__device__ __forceinline__ uint4 pack8(const float* f) {
    uint4 u;
    u.x = (unsigned)f2bf(f[0]) | ((unsigned)f2bf(f[1]) << 16);
    u.y = (unsigned)f2bf(f[2]) | ((unsigned)f2bf(f[3]) << 16);
    u.z = (unsigned)f2bf(f[4]) | ((unsigned)f2bf(f[5]) << 16);
    u.w = (unsigned)f2bf(f[6]) | ((unsigned)f2bf(f[7]) << 16);
    return u;
}

typedef __attribute__((address_space(3))) unsigned lds_u32;
typedef const __attribute__((address_space(1))) unsigned glb_u32;
__device__ __forceinline__ void gld16(const void* g, void* l) {
    __builtin_amdgcn_global_load_lds((glb_u32*)g, (lds_u32*)l, 16, 0, 0);
}

// ---------------------------------------------------------------- transpose
__global__ __launch_bounds__(256) void transpose_w(
    const float* __restrict__ wq, const float* __restrict__ wk,
    const float* __restrict__ wv, const float* __restrict__ wo,
    unsigned short* __restrict__ wcatT, unsigned short* __restrict__ woT)
{
    __shared__ unsigned short T[64 * 72];
    int bid = blockIdx.x;
    int p = bid >> 8;          // 0..3
    int t = bid & 255;
    int k0 = (t >> 4) * 64, n0 = (t & 15) * 64;
    const float* src = (p == 0) ? wq : (p == 1) ? wk : (p == 2) ? wv : wo;
    unsigned short* dst = (p < 3) ? (wcatT + (size_t)p * 1048576) : woT;
    int tid = threadIdx.x;
#pragma unroll
    for (int it = 0; it < 2; it++) {
        int flat = it * 2048 + tid * 8;
        int r = flat >> 6, c = flat & 63;
        const float* s4 = src + (size_t)(k0 + r) * 1024 + n0 + c;
        float4 u0 = *(const float4*)s4;
        float4 u1 = *(const float4*)(s4 + 4);
        float f[8] = {u0.x, u0.y, u0.z, u0.w, u1.x, u1.y, u1.z, u1.w};
        *(uint4*)&T[r * 72 + c] = pack8(f);
    }
    __syncthreads();
#pragma unroll
    for (int it = 0; it < 2; it++) {
        int flat = it * 2048 + tid * 8;
        int rn = flat >> 6, ck = flat & 63;
        unsigned short v[8];
#pragma unroll
        for (int j = 0; j < 8; j++) v[j] = T[(ck + j) * 72 + rn];
        uint4 u;
        u.x = (unsigned)v[0] | ((unsigned)v[1] << 16);
        u.y = (unsigned)v[2] | ((unsigned)v[3] << 16);
        u.z = (unsigned)v[4] | ((unsigned)v[5] << 16);
        u.w = (unsigned)v[6] | ((unsigned)v[7] << 16);
        *(uint4*)(dst + (size_t)(n0 + rn) * 1024 + k0 + ck) = u;
    }
}

// ---------------------------------------------------------------- layernorm
__global__ __launch_bounds__(256) void ln_kernel(
    const float* __restrict__ x, const float* __restrict__ gg,
    const float* __restrict__ bb, unsigned short* __restrict__ xn)
{
    int l = threadIdx.x & 63;
    size_t row = (size_t)blockIdx.x * 4 + (threadIdx.x >> 6);
    const float* xr = x + row * 1024;
    float f0[8], f1[8];
    *(float4*)&f0[0] = *(const float4*)(xr + l * 8);
    *(float4*)&f0[4] = *(const float4*)(xr + l * 8 + 4);
    *(float4*)&f1[0] = *(const float4*)(xr + 512 + l * 8);
    *(float4*)&f1[4] = *(const float4*)(xr + 512 + l * 8 + 4);
    float s = 0.f, s2 = 0.f;
#pragma unroll
    for (int j = 0; j < 8; j++) { s += f0[j] + f1[j]; s2 += f0[j] * f0[j] + f1[j] * f1[j]; }
#pragma unroll
    for (int m = 1; m < 64; m <<= 1) { s += __shfl_xor(s, m); s2 += __shfl_xor(s2, m); }
    float mu = s * (1.f / 1024.f);
    float var = s2 * (1.f / 1024.f) - mu * mu;
    float rs = rsqrtf(var + 1e-5f);
    float fg0[8], fg1[8], fb0[8], fb1[8];
    *(float4*)&fg0[0] = *(const float4*)(gg + l * 8);
    *(float4*)&fg0[4] = *(const float4*)(gg + l * 8 + 4);
    *(float4*)&fg1[0] = *(const float4*)(gg + 512 + l * 8);
    *(float4*)&fg1[4] = *(const float4*)(gg + 512 + l * 8 + 4);
    *(float4*)&fb0[0] = *(const float4*)(bb + l * 8);
    *(float4*)&fb0[4] = *(const float4*)(bb + l * 8 + 4);
    *(float4*)&fb1[0] = *(const float4*)(bb + 512 + l * 8);
    *(float4*)&fb1[4] = *(const float4*)(bb + 512 + l * 8 + 4);
    float o0[8], o1[8];
#pragma unroll
    for (int j = 0; j < 8; j++) {
        o0[j] = (f0[j] - mu) * rs * fg0[j] + fb0[j];
        o1[j] = (f1[j] - mu) * rs * fg1[j] + fb1[j];
    }
    *(uint4*)(xn + row * 1024 + l * 8) = pack8(o0);
    *(uint4*)(xn + row * 1024 + 512 + l * 8) = pack8(o1);
}

// ---------------------------------------------------------------- GEMM (m97 structure + T1 XCD swizzle)
// C[M, N=nt*128] = A[M,1024](bf16) @ Bt[N,1024]^T(bf16), K=1024.
// MODE 0: out(bf16) QKV scatter [proj][b_local][h][s][dk] + bias; proj stride = pstride
// MODE 1: out(f32) = acc + bias[col] + resid[row*1024+col]
template <int MODE>
__global__ __launch_bounds__(256) void gemm_bt(
    const unsigned short* __restrict__ A, const unsigned short* __restrict__ Bt,
    const float* __restrict__ bz0, const float* __restrict__ bz1,
    const float* __restrict__ bz2, const float* __restrict__ resid,
    void* __restrict__ outv, int nt, size_t pstride)
{
    __shared__ unsigned short sA[128 * 32];
    __shared__ unsigned short sB[128 * 32];
    // T1: XCD-aware swizzle (gridDim.x always a multiple of 8 here)
    int cpx = gridDim.x >> 3;
    int bid = (blockIdx.x & 7) * cpx + (blockIdx.x >> 3);
    int mt = bid / nt, ntile = bid % nt;
    int m0 = mt * 128, n0 = ntile * 128;
    int tid = threadIdx.x, l = tid & 63, w = tid >> 6;
    int wr = w >> 1, wc = w & 1;

    int chunk0 = w * 2, chunk1 = w * 2 + 1;
    int srow0 = chunk0 * 16 + (l >> 2), srow1 = chunk1 * 16 + (l >> 2);
    int scol = (l & 3) * 8;
    const unsigned short* Ar0 = A + (size_t)(m0 + srow0) * 1024 + scol;
    const unsigned short* Ar1 = A + (size_t)(m0 + srow1) * 1024 + scol;
    const unsigned short* Br0 = Bt + (size_t)(n0 + srow0) * 1024 + scol;
    const unsigned short* Br1 = Bt + (size_t)(n0 + srow1) * 1024 + scol;
    unsigned short* sA0 = sA + chunk0 * 512;
    unsigned short* sA1 = sA + chunk1 * 512;
    unsigned short* sB0 = sB + chunk0 * 512;
    unsigned short* sB1 = sB + chunk1 * 512;

    f32x4 acc[4][4];
#pragma unroll
    for (int i = 0; i < 4; i++)
#pragma unroll
        for (int j = 0; j < 4; j++)
#pragma unroll
            for (int v = 0; v < 4; v++) acc[i][j][v] = 0.f;

    int aoff = (wr * 64 + (l & 15)) * 32 + (l >> 4) * 8;
    int boff = (wc * 64 + (l & 15)) * 32 + (l >> 4) * 8;

    for (int kk = 0; kk < 1024; kk += 32) {
        __syncthreads();
        gld16(Ar0 + kk, sA0);
        gld16(Ar1 + kk, sA1);
        gld16(Br0 + kk, sB0);
        gld16(Br1 + kk, sB1);
        __syncthreads();
        bf16x8 aF[4], bF[4];
#pragma unroll
        for (int i = 0; i < 4; i++) aF[i] = *(const bf16x8*)(sA + aoff + i * 512);
#pragma unroll
        for (int j = 0; j < 4; j++) bF[j] = *(const bf16x8*)(sB + boff + j * 512);
#pragma unroll
        for (int i = 0; i < 4; i++)
#pragma unroll
            for (int j = 0; j < 4; j++)
                acc[i][j] = __builtin_amdgcn_mfma_f32_16x16x32_bf16(aF[i], bF[j], acc[i][j], 0, 0, 0);
    }

    if (MODE == 0) {
        unsigned short* out = (unsigned short*)outv;
        int p = n0 >> 10;  // block-uniform projection index (nt=24 -> N=3072)
        const float* bp = (p == 0) ? bz0 : (p == 1) ? bz1 : bz2;
        size_t pbase = (size_t)p * pstride;
#pragma unroll
        for (int j = 0; j < 4; j++) {
            int colg = n0 + wc * 64 + j * 16 + (l & 15);
            int nn = colg & 1023;
            float bias = bp[nn];
            int hh = nn >> 6, dk = nn & 63;
#pragma unroll
            for (int i = 0; i < 4; i++)
#pragma unroll
                for (int v = 0; v < 4; v++) {
                    int rowg = m0 + wr * 64 + i * 16 + (l >> 4) * 4 + v;  // chunk-local
                    int b_ = rowg >> 5, s_ = rowg & 31;                    // local batch
                    out[pbase + ((size_t)((b_ * 16 + hh) * 32 + s_) << 6) + dk] =
                        f2bf(acc[i][j][v] + bias);
                }
        }
    } else {
        float* out = (float*)outv;
#pragma unroll
        for (int j = 0; j < 4; j++) {
            int colg = n0 + wc * 64 + j * 16 + (l & 15);
            float bias = bz0[colg];
#pragma unroll
            for (int i = 0; i < 4; i++)
#pragma unroll
                for (int v = 0; v < 4; v++) {
                    int rowg = m0 + wr * 64 + i * 16 + (l >> 4) * 4 + v;
                    size_t idx = (size_t)rowg * 1024 + colg;
                    out[idx] = acc[i][j][v] + bias + resid[idx];
                }
        }
    }
}

// ---------------------------------------------------------------- attention
// 256 threads = 4 waves; each wave handles one (b_local, h).
// QKV chunk layout: [proj][b_local][h][s=32][dk=64] bf16, proj stride = pstride.
__global__ __launch_bounds__(256) void attn_kernel(
    const unsigned short* __restrict__ qkv, const float* __restrict__ rb,
    unsigned short* __restrict__ ctx, size_t pstride)
{
    __shared__ float Vs[4][32 * 68];
    __shared__ float Ps[4][32 * 33];
    int sb = threadIdx.x >> 6, l = threadIdx.x & 63;
    int col = l & 31, hi = l >> 5;
    int bh = blockIdx.x * 4 + sb, h = bh & 15;
    size_t base = (size_t)bh << 11;  // *2048
    const unsigned short* Qb = qkv + base;
    const unsigned short* Kb = Qb + pstride;
    const unsigned short* Vb = Kb + pstride;
    float* Vw = Vs[sb];
    float* Pw = Ps[sb];

    // stage V -> LDS f32 [32][68]
#pragma unroll
    for (int i = 0; i < 4; i++) {
        int flat = i * 512 + l * 8;
        int s = flat >> 6, d = flat & 63;
        uint4 u = *(const uint4*)(Vb + flat);
        Vw[s * 68 + d + 0] = bf2f((unsigned short)(u.x & 0xFFFF));
        Vw[s * 68 + d + 1] = bf2f((unsigned short)(u.x >> 16));
        Vw[s * 68 + d + 2] = bf2f((unsigned short)(u.y & 0xFFFF));
        Vw[s * 68 + d + 3] = bf2f((unsigned short)(u.y >> 16));
        Vw[s * 68 + d + 4] = bf2f((unsigned short)(u.z & 0xFFFF));
        Vw[s * 68 + d + 5] = bf2f((unsigned short)(u.z >> 16));
        Vw[s * 68 + d + 6] = bf2f((unsigned short)(u.w & 0xFFFF));
        Vw[s * 68 + d + 7] = bf2f((unsigned short)(u.w >> 16));
    }

    // QK^T via mfma_32x32x16: A row = lane&31 (q), B col = lane&31 (k),
    // k_frag = (lane>>5)*8 + j; 4 steps cover DK=64.
    f32x16 acc;
#pragma unroll
    for (int i = 0; i < 16; i++) acc[i] = 0.f;
#pragma unroll
    for (int t = 0; t < 4; t++) {
        bf16x8 aQ = *(const bf16x8*)(Qb + col * 64 + t * 16 + hi * 8);
        bf16x8 bK = *(const bf16x8*)(Kb + col * 64 + t * 16 + hi * 8);
        acc = __builtin_amdgcn_mfma_f32_32x32x16_bf16(aQ, bK, acc, 0, 0, 0);
    }

    // scale + rel_bias + row softmax; C/D row = (r&3)+8*(r>>2)+4*hi, col = lane&31
    const float* rbh = rb + h * 1024;
#pragma unroll
    for (int r = 0; r < 16; r++) {
        int m = (r & 3) + 8 * (r >> 2) + 4 * hi;
        float v = acc[r] * 0.125f + rbh[m * 32 + col];
        float mx = v;
#pragma unroll
        for (int msk = 1; msk < 32; msk <<= 1) mx = fmaxf(mx, __shfl_xor(mx, msk));
        float e = __expf(v - mx);
        float sm = e;
#pragma unroll
        for (int msk = 1; msk < 32; msk <<= 1) sm += __shfl_xor(sm, msk);
        Pw[m * 33 + col] = e / sm;
    }
    __syncthreads();

    // PV: lane -> (q = l>>1, d-block of 32)
    int q = l >> 1, dblk = (l & 1) << 5;
    float o[32];
#pragma unroll
    for (int d = 0; d < 32; d++) o[d] = 0.f;
    for (int k = 0; k < 32; k++) {
        float pv = Pw[q * 33 + k];
#pragma unroll
        for (int j = 0; j < 8; j++) {
            float4 v4 = *(const float4*)&Vw[k * 68 + dblk + j * 4];
            o[j * 4 + 0] += pv * v4.x;
            o[j * 4 + 1] += pv * v4.y;
            o[j * 4 + 2] += pv * v4.z;
            o[j * 4 + 3] += pv * v4.w;
        }
    }
    // ctx row (chunk-local) = b_local*32 + q, col = h*64 + dblk .. +31 (bf16)
    size_t ob = ((size_t)(bh >> 4) * 32 + q) * 1024 + h * 64 + dblk;
#pragma unroll
    for (int j = 0; j < 4; j++) *(uint4*)(ctx + ob + j * 8) = pack8(&o[j * 8]);
}

// ---------------------------------------------------------------- launch
extern "C" void kernel_launch(void* const* d_in, const int* in_sizes, int n_in,
                              void* d_out, int out_size, void* d_ws, size_t ws_size,
                              hipStream_t stream)
{
    const float* x  = (const float*)d_in[0];
    const float* lg = (const float*)d_in[1];
    const float* lb = (const float*)d_in[2];
    const float* wq = (const float*)d_in[3];
    const float* bq = (const float*)d_in[4];
    const float* wk = (const float*)d_in[5];
    const float* bk = (const float*)d_in[6];
    const float* wv = (const float*)d_in[7];
    const float* bv = (const float*)d_in[8];
    const float* wo = (const float*)d_in[9];
    const float* bo = (const float*)d_in[10];
    const float* rb = (const float*)d_in[11];
    float* out = (float*)d_out;
    unsigned short* ws = (unsigned short*)d_ws;

    unsigned short* wcatT = ws;                        // 3072*1024
    unsigned short* woT   = wcatT + 3145728;           // 1024*1024
    unsigned short* xnctx = woT + 1048576;             // 65536*1024 (xn, then ctx in place)
    unsigned short* qkvc  = xnctx + 67108864ull;       // QKV chunk buffer

    // Adaptive chunking: 4 chunks of 512 batches if ws fits, else 8 of 256.
    const size_t need4 = (3145728ull + 1048576ull + 67108864ull + 50331648ull) * 2;
    int nChunks  = (ws_size >= need4) ? 4 : 8;
    int rowsPer  = 65536 / nChunks;            // 16384 or 8192
    size_t pstr  = (size_t)rowsPer * 1024;     // per-projection stride in qkv chunk

    transpose_w<<<dim3(1024), dim3(256), 0, stream>>>(wq, wk, wv, wo, wcatT, woT);
    ln_kernel<<<dim3(16384), dim3(256), 0, stream>>>(x, lg, lb, xnctx);

    int gemm0Grid = (rowsPer / 128) * 24;      // 3072 or 1536 (multiple of 8)
    int attnGrid  = (rowsPer / 32) * 16 / 4;   // bh pairs / 4 waves per block

    for (int c = 0; c < nChunks; c++) {
        const unsigned short* Ac = xnctx + (size_t)c * pstr;
        unsigned short* ctxc = xnctx + (size_t)c * pstr;
        gemm_bt<0><<<dim3(gemm0Grid), dim3(256), 0, stream>>>(
            Ac, wcatT, bq, bk, bv, (const float*)nullptr, (void*)qkvc, 24, pstr);
        attn_kernel<<<dim3(attnGrid), dim3(256), 0, stream>>>(qkvc, rb, ctxc, pstr);
    }

    gemm_bt<1><<<dim3(4096), dim3(256), 0, stream>>>(
        xnctx, woT, bo, bo, bo, x, (void*)out, 8, 0);
}

// Round 4
// 1010.858 us; speedup vs baseline: 1.1343x; 1.0841x over previous
//
#include <hip/hip_runtime.h>
#include <stdint.h>

// B=2048, S=32, D=1024, H=16, DK=64. d_in/d_out FLOAT32; internal bf16.
// Pipeline: transpose_w -> ln -> Nc x( gemm8<QKV chunk> -> attn ) -> gemm8<OUT>.
// gemm8: 256x256 tile, BK=64, 8 waves, 8-phase counted-vmcnt schedule (T2+T3+T4+T5).

typedef __attribute__((ext_vector_type(8))) short bf16x8;
typedef __attribute__((ext_vector_type(4))) float f32x4;
typedef __attribute__((ext_vector_type(16))) float f32x16;

__device__ __forceinline__ float bf2f(unsigned short u) {
    return __uint_as_float(((unsigned)u) << 16);
}
__device__ __forceinline__ unsigned short f2bf(float f) {
    unsigned u = __float_as_uint(f);
    u += 0x7FFFu + ((u >> 16) & 1u);
    return (unsigned short)(u >> 16);
}
__device__ __forceinline__ uint4 pack8(const float* f) {
    uint4 u;
    u.x = (unsigned)f2bf(f[0]) | ((unsigned)f2bf(f[1]) << 16);
    u.y = (unsigned)f2bf(f[2]) | ((unsigned)f2bf(f[3]) << 16);
    u.z = (unsigned)f2bf(f[4]) | ((unsigned)f2bf(f[5]) << 16);
    u.w = (unsigned)f2bf(f[6]) | ((unsigned)f2bf(f[7]) << 16);
    return u;
}

typedef __attribute__((address_space(3))) unsigned lds_u32;
typedef const __attribute__((address_space(1))) unsigned glb_u32;
__device__ __forceinline__ void gld16(const void* g, void* l) {
    __builtin_amdgcn_global_load_lds((glb_u32*)g, (lds_u32*)l, 16, 0, 0);
}

// ---------------------------------------------------------------- transpose
__global__ __launch_bounds__(256) void transpose_w(
    const float* __restrict__ wq, const float* __restrict__ wk,
    const float* __restrict__ wv, const float* __restrict__ wo,
    unsigned short* __restrict__ wcatT, unsigned short* __restrict__ woT)
{
    __shared__ unsigned short T[64 * 72];
    int bid = blockIdx.x;
    int p = bid >> 8;
    int t = bid & 255;
    int k0 = (t >> 4) * 64, n0 = (t & 15) * 64;
    const float* src = (p == 0) ? wq : (p == 1) ? wk : (p == 2) ? wv : wo;
    unsigned short* dst = (p < 3) ? (wcatT + (size_t)p * 1048576) : woT;
    int tid = threadIdx.x;
#pragma unroll
    for (int it = 0; it < 2; it++) {
        int flat = it * 2048 + tid * 8;
        int r = flat >> 6, c = flat & 63;
        const float* s4 = src + (size_t)(k0 + r) * 1024 + n0 + c;
        float4 u0 = *(const float4*)s4;
        float4 u1 = *(const float4*)(s4 + 4);
        float f[8] = {u0.x, u0.y, u0.z, u0.w, u1.x, u1.y, u1.z, u1.w};
        *(uint4*)&T[r * 72 + c] = pack8(f);
    }
    __syncthreads();
#pragma unroll
    for (int it = 0; it < 2; it++) {
        int flat = it * 2048 + tid * 8;
        int rn = flat >> 6, ck = flat & 63;
        unsigned short v[8];
#pragma unroll
        for (int j = 0; j < 8; j++) v[j] = T[(ck + j) * 72 + rn];
        uint4 u;
        u.x = (unsigned)v[0] | ((unsigned)v[1] << 16);
        u.y = (unsigned)v[2] | ((unsigned)v[3] << 16);
        u.z = (unsigned)v[4] | ((unsigned)v[5] << 16);
        u.w = (unsigned)v[6] | ((unsigned)v[7] << 16);
        *(uint4*)(dst + (size_t)(n0 + rn) * 1024 + k0 + ck) = u;
    }
}

// ---------------------------------------------------------------- layernorm
__global__ __launch_bounds__(256) void ln_kernel(
    const float* __restrict__ x, const float* __restrict__ gg,
    const float* __restrict__ bb, unsigned short* __restrict__ xn)
{
    int l = threadIdx.x & 63;
    size_t row = (size_t)blockIdx.x * 4 + (threadIdx.x >> 6);
    const float* xr = x + row * 1024;
    float f0[8], f1[8];
    *(float4*)&f0[0] = *(const float4*)(xr + l * 8);
    *(float4*)&f0[4] = *(const float4*)(xr + l * 8 + 4);
    *(float4*)&f1[0] = *(const float4*)(xr + 512 + l * 8);
    *(float4*)&f1[4] = *(const float4*)(xr + 512 + l * 8 + 4);
    float s = 0.f, s2 = 0.f;
#pragma unroll
    for (int j = 0; j < 8; j++) { s += f0[j] + f1[j]; s2 += f0[j] * f0[j] + f1[j] * f1[j]; }
#pragma unroll
    for (int m = 1; m < 64; m <<= 1) { s += __shfl_xor(s, m); s2 += __shfl_xor(s2, m); }
    float mu = s * (1.f / 1024.f);
    float var = s2 * (1.f / 1024.f) - mu * mu;
    float rs = rsqrtf(var + 1e-5f);
    float fg0[8], fg1[8], fb0[8], fb1[8];
    *(float4*)&fg0[0] = *(const float4*)(gg + l * 8);
    *(float4*)&fg0[4] = *(const float4*)(gg + l * 8 + 4);
    *(float4*)&fg1[0] = *(const float4*)(gg + 512 + l * 8);
    *(float4*)&fg1[4] = *(const float4*)(gg + 512 + l * 8 + 4);
    *(float4*)&fb0[0] = *(const float4*)(bb + l * 8);
    *(float4*)&fb0[4] = *(const float4*)(bb + l * 8 + 4);
    *(float4*)&fb1[0] = *(const float4*)(bb + 512 + l * 8);
    *(float4*)&fb1[4] = *(const float4*)(bb + 512 + l * 8 + 4);
    float o0[8], o1[8];
#pragma unroll
    for (int j = 0; j < 8; j++) {
        o0[j] = (f0[j] - mu) * rs * fg0[j] + fb0[j];
        o1[j] = (f1[j] - mu) * rs * fg1[j] + fb1[j];
    }
    *(uint4*)(xn + row * 1024 + l * 8) = pack8(o0);
    *(uint4*)(xn + row * 1024 + 512 + l * 8) = pack8(o1);
}

// ---------------------------------------------------------------- gemm8
// C[M, N=NTL*256] = A[M,1024] @ Bt[N,1024]^T (bf16), K=1024.
// 512 threads = 8 waves (2M x 4N); per-wave out 128x64 = 8x4 frags 16x16.
// LDS: double-buffered A/B tiles [2][256][64] bf16 = 128 KiB.
// T2 swizzle: LDS col ^= (row&7)<<3 (applied via pre-swizzled global source
// for the linear global_load_lds dest, and the same XOR on ds_read).
// Stage slots per iteration (tiles T=2it, T+1): ph1,2: A(T+1)->buf1;
// ph3,4: B(T+2)->buf0; ph5,6: A(T+2)->buf0; ph7,8: B(T+3)->buf1.
// vmcnt(4) at ph4/ph8 only (2 half-tiles in flight), vmcnt(0) in final iter.

#define FENCE asm volatile("" ::: "memory")
#define BARRIER do { FENCE; __builtin_amdgcn_s_barrier(); FENCE; } while (0)
#define WAIT_LGKM0 do { asm volatile("s_waitcnt lgkmcnt(0)" ::: "memory"); \
                        __builtin_amdgcn_sched_barrier(0); } while (0)
#define VMCNT(n) asm volatile("s_waitcnt vmcnt(" #n ")" ::: "memory")

#define STG(gb, h, kcol, ldsreg) do { \
    const unsigned short* _g = (gb) + (size_t)((h) * 128) * 1024 + (kcol); \
    unsigned short* _d = (ldsreg) + ((h) * 128 + w * 8) * 64; \
    gld16(_g, _d); gld16(_g + 64 * 1024, _d + 64 * 64); } while (0)

#define LDA(buf, q, rfq, ks) (*(const bf16x8*)&sAl[buf][ \
    (wm * 128 + (q) * 32 + (rfq) * 16 + (l & 15)) * 64 + ((((ks) * 32) + khi) ^ aswz)])
#define LDB(buf, cf, ks) (*(const bf16x8*)&sBl[buf][ \
    (wn * 64 + (cf) * 16 + (l & 15)) * 64 + ((((ks) * 32) + khi) ^ aswz)])

#define MFMA_QUAD(q) do { \
    _Pragma("unroll") \
    for (int cf = 0; cf < 4; cf++) { \
        acc[(q)*2+0][cf] = __builtin_amdgcn_mfma_f32_16x16x32_bf16(aF00, bF[cf][0], acc[(q)*2+0][cf], 0, 0, 0); \
        acc[(q)*2+0][cf] = __builtin_amdgcn_mfma_f32_16x16x32_bf16(aF01, bF[cf][1], acc[(q)*2+0][cf], 0, 0, 0); \
        acc[(q)*2+1][cf] = __builtin_amdgcn_mfma_f32_16x16x32_bf16(aF10, bF[cf][0], acc[(q)*2+1][cf], 0, 0, 0); \
        acc[(q)*2+1][cf] = __builtin_amdgcn_mfma_f32_16x16x32_bf16(aF11, bF[cf][1], acc[(q)*2+1][cf], 0, 0, 0); \
    } } while (0)

#define PHASE(buf, q, STAGE_STMT, TAIL_STMT) do { \
    bf16x8 aF00 = LDA(buf, q, 0, 0), aF01 = LDA(buf, q, 0, 1); \
    bf16x8 aF10 = LDA(buf, q, 1, 0), aF11 = LDA(buf, q, 1, 1); \
    if ((q) == 0) { \
        _Pragma("unroll") \
        for (int cf = 0; cf < 4; cf++) { bF[cf][0] = LDB(buf, cf, 0); bF[cf][1] = LDB(buf, cf, 1); } \
    } \
    STAGE_STMT; \
    BARRIER; \
    WAIT_LGKM0; \
    __builtin_amdgcn_s_setprio(1); \
    MFMA_QUAD(q); \
    __builtin_amdgcn_s_setprio(0); \
    TAIL_STMT; \
    BARRIER; \
} while (0)

template <int MODE>
__global__ __launch_bounds__(512, 2) void gemm8(
    const unsigned short* __restrict__ A, const unsigned short* __restrict__ Bt,
    const float* __restrict__ bz0, const float* __restrict__ bz1,
    const float* __restrict__ bz2, const float* __restrict__ resid,
    void* __restrict__ outv, int NTL, size_t pstride)
{
    __shared__ unsigned short sAl[2][256 * 64];
    __shared__ unsigned short sBl[2][256 * 64];
    int cpx = gridDim.x >> 3;
    int bid = (blockIdx.x & 7) * cpx + (blockIdx.x >> 3);  // T1 XCD swizzle
    int mt = bid / NTL, ntl = bid % NTL;
    int m0 = mt * 256, n0 = ntl * 256;
    int tid = threadIdx.x, l = tid & 63, w = tid >> 6;
    int wm = w >> 2, wn = w & 3;
    int khi = (l >> 4) * 8;
    int aswz = (l & 7) * 8;

    // Pre-swizzled per-lane global staging base (rule #21: linear LDS dest,
    // inverse-swizzled source, swizzled read).
    const unsigned short* Ag = A + (size_t)(m0 + w * 8 + (l >> 3)) * 1024 + ((l & 7) ^ (l >> 3)) * 8;
    const unsigned short* Bg = Bt + (size_t)(n0 + w * 8 + (l >> 3)) * 1024 + ((l & 7) ^ (l >> 3)) * 8;
    unsigned short* sA0 = &sAl[0][0];
    unsigned short* sA1 = &sAl[1][0];
    unsigned short* sB0 = &sBl[0][0];
    unsigned short* sB1 = &sBl[1][0];

    f32x4 acc[8][4];
#pragma unroll
    for (int i = 0; i < 8; i++)
#pragma unroll
        for (int j = 0; j < 4; j++)
#pragma unroll
            for (int v = 0; v < 4; v++) acc[i][j][v] = 0.f;

    bf16x8 bF[4][2];

    // Prologue: A(0),B(0) -> buf0; B(1) -> buf1. Allow B(1) in flight.
    STG(Ag, 0, 0, sA0); STG(Ag, 1, 0, sA0);
    STG(Bg, 0, 0, sB0); STG(Bg, 1, 0, sB0);
    STG(Bg, 0, 64, sB1); STG(Bg, 1, 64, sB1);
    VMCNT(4);
    BARRIER;

    // Main loop: iterations 0..6, tiles (2it, 2it+1); K advances 128/iter.
    for (int it = 0; it < 7; ++it) {
        int koff = it * 128;
        PHASE(0, 0, STG(Ag, 0, koff + 64, sA1), (void)0);
        PHASE(0, 1, STG(Ag, 1, koff + 64, sA1), (void)0);
        PHASE(0, 2, STG(Bg, 0, koff + 128, sB0), (void)0);
        PHASE(0, 3, STG(Bg, 1, koff + 128, sB0), VMCNT(4));
        PHASE(1, 0, STG(Ag, 0, koff + 128, sA0), (void)0);
        PHASE(1, 1, STG(Ag, 1, koff + 128, sA0), (void)0);
        PHASE(1, 2, STG(Bg, 0, koff + 192, sB1), (void)0);
        PHASE(1, 3, STG(Bg, 1, koff + 192, sB1), VMCNT(4));
    }
    // Final iteration (tiles 14,15): only A(15) remains to stage.
    PHASE(0, 0, STG(Ag, 0, 960, sA1), (void)0);
    PHASE(0, 1, STG(Ag, 1, 960, sA1), (void)0);
    PHASE(0, 2, (void)0, (void)0);
    PHASE(0, 3, (void)0, VMCNT(0));
    PHASE(1, 0, (void)0, (void)0);
    PHASE(1, 1, (void)0, (void)0);
    PHASE(1, 2, (void)0, (void)0);
    PHASE(1, 3, (void)0, (void)0);
    __builtin_amdgcn_sched_barrier(0);

    // Epilogue. C/D frag: row = +(l>>4)*4+v, col = +(l&15).
    if (MODE == 0) {
        unsigned short* out = (unsigned short*)outv;
        int p = n0 >> 10;  // block-uniform (n0 multiple of 256)
        const float* bp = (p == 0) ? bz0 : (p == 1) ? bz1 : bz2;
        size_t pbase = (size_t)p * pstride;
#pragma unroll
        for (int cf = 0; cf < 4; cf++) {
            int colg = n0 + wn * 64 + cf * 16 + (l & 15);
            int nn = colg & 1023;
            float bias = bp[nn];
            int hh = nn >> 6, dk = nn & 63;
#pragma unroll
            for (int rf = 0; rf < 8; rf++) {
#pragma unroll
                for (int v = 0; v < 4; v++) {
                    int rowg = m0 + wm * 128 + rf * 16 + (l >> 4) * 4 + v;
                    int b_ = rowg >> 5, s_ = rowg & 31;
                    out[pbase + ((size_t)((b_ * 16 + hh) * 32 + s_) << 6) + dk] =
                        f2bf(acc[rf][cf][v] + bias);
                }
            }
        }
    } else {
        float* out = (float*)outv;
#pragma unroll
        for (int cf = 0; cf < 4; cf++) {
            int colg = n0 + wn * 64 + cf * 16 + (l & 15);
            float bias = bz0[colg];
#pragma unroll
            for (int rf = 0; rf < 8; rf++) {
#pragma unroll
                for (int v = 0; v < 4; v++) {
                    int rowg = m0 + wm * 128 + rf * 16 + (l >> 4) * 4 + v;
                    size_t idx = (size_t)rowg * 1024 + colg;
                    out[idx] = acc[rf][cf][v] + bias + resid[idx];
                }
            }
        }
    }
}

// ---------------------------------------------------------------- attention
__global__ __launch_bounds__(256) void attn_kernel(
    const unsigned short* __restrict__ qkv, const float* __restrict__ rb,
    unsigned short* __restrict__ ctx, size_t pstride)
{
    __shared__ float Vs[4][32 * 68];
    __shared__ float Ps[4][32 * 33];
    int sb = threadIdx.x >> 6, l = threadIdx.x & 63;
    int col = l & 31, hi = l >> 5;
    int bh = blockIdx.x * 4 + sb, h = bh & 15;
    size_t base = (size_t)bh << 11;
    const unsigned short* Qb = qkv + base;
    const unsigned short* Kb = Qb + pstride;
    const unsigned short* Vb = Kb + pstride;
    float* Vw = Vs[sb];
    float* Pw = Ps[sb];

#pragma unroll
    for (int i = 0; i < 4; i++) {
        int flat = i * 512 + l * 8;
        int s = flat >> 6, d = flat & 63;
        uint4 u = *(const uint4*)(Vb + flat);
        Vw[s * 68 + d + 0] = bf2f((unsigned short)(u.x & 0xFFFF));
        Vw[s * 68 + d + 1] = bf2f((unsigned short)(u.x >> 16));
        Vw[s * 68 + d + 2] = bf2f((unsigned short)(u.y & 0xFFFF));
        Vw[s * 68 + d + 3] = bf2f((unsigned short)(u.y >> 16));
        Vw[s * 68 + d + 4] = bf2f((unsigned short)(u.z & 0xFFFF));
        Vw[s * 68 + d + 5] = bf2f((unsigned short)(u.z >> 16));
        Vw[s * 68 + d + 6] = bf2f((unsigned short)(u.w & 0xFFFF));
        Vw[s * 68 + d + 7] = bf2f((unsigned short)(u.w >> 16));
    }

    f32x16 acc;
#pragma unroll
    for (int i = 0; i < 16; i++) acc[i] = 0.f;
#pragma unroll
    for (int t = 0; t < 4; t++) {
        bf16x8 aQ = *(const bf16x8*)(Qb + col * 64 + t * 16 + hi * 8);
        bf16x8 bK = *(const bf16x8*)(Kb + col * 64 + t * 16 + hi * 8);
        acc = __builtin_amdgcn_mfma_f32_32x32x16_bf16(aQ, bK, acc, 0, 0, 0);
    }

    const float* rbh = rb + h * 1024;
#pragma unroll
    for (int r = 0; r < 16; r++) {
        int m = (r & 3) + 8 * (r >> 2) + 4 * hi;
        float v = acc[r] * 0.125f + rbh[m * 32 + col];
        float mx = v;
#pragma unroll
        for (int msk = 1; msk < 32; msk <<= 1) mx = fmaxf(mx, __shfl_xor(mx, msk));
        float e = __expf(v - mx);
        float sm = e;
#pragma unroll
        for (int msk = 1; msk < 32; msk <<= 1) sm += __shfl_xor(sm, msk);
        Pw[m * 33 + col] = e / sm;
    }
    __syncthreads();

    int q = l >> 1, dblk = (l & 1) << 5;
    float o[32];
#pragma unroll
    for (int d = 0; d < 32; d++) o[d] = 0.f;
    for (int k = 0; k < 32; k++) {
        float pv = Pw[q * 33 + k];
#pragma unroll
        for (int j = 0; j < 8; j++) {
            float4 v4 = *(const float4*)&Vw[k * 68 + dblk + j * 4];
            o[j * 4 + 0] += pv * v4.x;
            o[j * 4 + 1] += pv * v4.y;
            o[j * 4 + 2] += pv * v4.z;
            o[j * 4 + 3] += pv * v4.w;
        }
    }
    size_t ob = ((size_t)(bh >> 4) * 32 + q) * 1024 + h * 64 + dblk;
#pragma unroll
    for (int j = 0; j < 4; j++) *(uint4*)(ctx + ob + j * 8) = pack8(&o[j * 8]);
}

// ---------------------------------------------------------------- launch
extern "C" void kernel_launch(void* const* d_in, const int* in_sizes, int n_in,
                              void* d_out, int out_size, void* d_ws, size_t ws_size,
                              hipStream_t stream)
{
    const float* x  = (const float*)d_in[0];
    const float* lg = (const float*)d_in[1];
    const float* lb = (const float*)d_in[2];
    const float* wq = (const float*)d_in[3];
    const float* bq = (const float*)d_in[4];
    const float* wk = (const float*)d_in[5];
    const float* bk = (const float*)d_in[6];
    const float* wv = (const float*)d_in[7];
    const float* bv = (const float*)d_in[8];
    const float* wo = (const float*)d_in[9];
    const float* bo = (const float*)d_in[10];
    const float* rb = (const float*)d_in[11];
    float* out = (float*)d_out;
    unsigned short* ws = (unsigned short*)d_ws;

    unsigned short* wcatT = ws;                        // 3072*1024
    unsigned short* woT   = wcatT + 3145728;           // 1024*1024
    unsigned short* xnctx = woT + 1048576;             // 65536*1024 (xn -> ctx in place)
    unsigned short* qkvc  = xnctx + 67108864ull;       // QKV chunk buffer

    const size_t need4 = (3145728ull + 1048576ull + 67108864ull + 50331648ull) * 2;
    int nChunks  = (ws_size >= need4) ? 4 : 8;
    int rowsPer  = 65536 / nChunks;            // 16384 or 8192 (multiple of 256)
    size_t pstr  = (size_t)rowsPer * 1024;

    transpose_w<<<dim3(1024), dim3(256), 0, stream>>>(wq, wk, wv, wo, wcatT, woT);
    ln_kernel<<<dim3(16384), dim3(256), 0, stream>>>(x, lg, lb, xnctx);

    int gemm0Grid = (rowsPer / 256) * 12;      // 768 or 384 (multiple of 8)
    int attnGrid  = (rowsPer / 32) * 16 / 4;

    for (int c = 0; c < nChunks; c++) {
        const unsigned short* Ac = xnctx + (size_t)c * pstr;
        unsigned short* ctxc = xnctx + (size_t)c * pstr;
        gemm8<0><<<dim3(gemm0Grid), dim3(512), 0, stream>>>(
            Ac, wcatT, bq, bk, bv, (const float*)nullptr, (void*)qkvc, 12, pstr);
        attn_kernel<<<dim3(attnGrid), dim3(256), 0, stream>>>(qkvc, rb, ctxc, pstr);
    }

    gemm8<1><<<dim3(1024), dim3(512), 0, stream>>>(
        xnctx, woT, bo, bo, bo, x, (void*)out, 4, 0);
}

// Round 5
// 798.883 us; speedup vs baseline: 1.4352x; 1.2653x over previous
//
#include <hip/hip_runtime.h>
#include <stdint.h>

// B=2048, S=32, D=1024, H=16, DK=64. d_in/d_out FLOAT32; internal bf16.
// Pipeline: transpose_w -> ln -> Nc x( gemm8<QKV chunk> -> attn ) -> gemm8<OUT>.
// gemm8: 256x256, BK=64, 8 waves, 8-phase counted-vmcnt (T1+T2+T3+T4+T5),
//        LDS-repack coalesced epilogues. attn: MFMA QK^T + MFMA PV, bf16 LDS.

typedef __attribute__((ext_vector_type(8))) short bf16x8;
typedef __attribute__((ext_vector_type(4))) float f32x4;
typedef __attribute__((ext_vector_type(16))) float f32x16;

__device__ __forceinline__ float bf2f(unsigned short u) {
    return __uint_as_float(((unsigned)u) << 16);
}
__device__ __forceinline__ unsigned short f2bf(float f) {
    unsigned u = __float_as_uint(f);
    u += 0x7FFFu + ((u >> 16) & 1u);
    return (unsigned short)(u >> 16);
}
__device__ __forceinline__ uint4 pack8(const float* f) {
    uint4 u;
    u.x = (unsigned)f2bf(f[0]) | ((unsigned)f2bf(f[1]) << 16);
    u.y = (unsigned)f2bf(f[2]) | ((unsigned)f2bf(f[3]) << 16);
    u.z = (unsigned)f2bf(f[4]) | ((unsigned)f2bf(f[5]) << 16);
    u.w = (unsigned)f2bf(f[6]) | ((unsigned)f2bf(f[7]) << 16);
    return u;
}

typedef __attribute__((address_space(3))) unsigned lds_u32;
typedef const __attribute__((address_space(1))) unsigned glb_u32;
__device__ __forceinline__ void gld16(const void* g, void* l) {
    __builtin_amdgcn_global_load_lds((glb_u32*)g, (lds_u32*)l, 16, 0, 0);
}

// ---------------------------------------------------------------- transpose
__global__ __launch_bounds__(256) void transpose_w(
    const float* __restrict__ wq, const float* __restrict__ wk,
    const float* __restrict__ wv, const float* __restrict__ wo,
    unsigned short* __restrict__ wcatT, unsigned short* __restrict__ woT)
{
    __shared__ unsigned short T[64 * 72];
    int bid = blockIdx.x;
    int p = bid >> 8;
    int t = bid & 255;
    int k0 = (t >> 4) * 64, n0 = (t & 15) * 64;
    const float* src = (p == 0) ? wq : (p == 1) ? wk : (p == 2) ? wv : wo;
    unsigned short* dst = (p < 3) ? (wcatT + (size_t)p * 1048576) : woT;
    int tid = threadIdx.x;
#pragma unroll
    for (int it = 0; it < 2; it++) {
        int flat = it * 2048 + tid * 8;
        int r = flat >> 6, c = flat & 63;
        const float* s4 = src + (size_t)(k0 + r) * 1024 + n0 + c;
        float4 u0 = *(const float4*)s4;
        float4 u1 = *(const float4*)(s4 + 4);
        float f[8] = {u0.x, u0.y, u0.z, u0.w, u1.x, u1.y, u1.z, u1.w};
        *(uint4*)&T[r * 72 + c] = pack8(f);
    }
    __syncthreads();
#pragma unroll
    for (int it = 0; it < 2; it++) {
        int flat = it * 2048 + tid * 8;
        int rn = flat >> 6, ck = flat & 63;
        unsigned short v[8];
#pragma unroll
        for (int j = 0; j < 8; j++) v[j] = T[(ck + j) * 72 + rn];
        uint4 u;
        u.x = (unsigned)v[0] | ((unsigned)v[1] << 16);
        u.y = (unsigned)v[2] | ((unsigned)v[3] << 16);
        u.z = (unsigned)v[4] | ((unsigned)v[5] << 16);
        u.w = (unsigned)v[6] | ((unsigned)v[7] << 16);
        *(uint4*)(dst + (size_t)(n0 + rn) * 1024 + k0 + ck) = u;
    }
}

// ---------------------------------------------------------------- layernorm
__global__ __launch_bounds__(256) void ln_kernel(
    const float* __restrict__ x, const float* __restrict__ gg,
    const float* __restrict__ bb, unsigned short* __restrict__ xn)
{
    int l = threadIdx.x & 63;
    size_t row = (size_t)blockIdx.x * 4 + (threadIdx.x >> 6);
    const float* xr = x + row * 1024;
    float f0[8], f1[8];
    *(float4*)&f0[0] = *(const float4*)(xr + l * 8);
    *(float4*)&f0[4] = *(const float4*)(xr + l * 8 + 4);
    *(float4*)&f1[0] = *(const float4*)(xr + 512 + l * 8);
    *(float4*)&f1[4] = *(const float4*)(xr + 512 + l * 8 + 4);
    float s = 0.f, s2 = 0.f;
#pragma unroll
    for (int j = 0; j < 8; j++) { s += f0[j] + f1[j]; s2 += f0[j] * f0[j] + f1[j] * f1[j]; }
#pragma unroll
    for (int m = 1; m < 64; m <<= 1) { s += __shfl_xor(s, m); s2 += __shfl_xor(s2, m); }
    float mu = s * (1.f / 1024.f);
    float var = s2 * (1.f / 1024.f) - mu * mu;
    float rs = rsqrtf(var + 1e-5f);
    float fg0[8], fg1[8], fb0[8], fb1[8];
    *(float4*)&fg0[0] = *(const float4*)(gg + l * 8);
    *(float4*)&fg0[4] = *(const float4*)(gg + l * 8 + 4);
    *(float4*)&fg1[0] = *(const float4*)(gg + 512 + l * 8);
    *(float4*)&fg1[4] = *(const float4*)(gg + 512 + l * 8 + 4);
    *(float4*)&fb0[0] = *(const float4*)(bb + l * 8);
    *(float4*)&fb0[4] = *(const float4*)(bb + l * 8 + 4);
    *(float4*)&fb1[0] = *(const float4*)(bb + 512 + l * 8);
    *(float4*)&fb1[4] = *(const float4*)(bb + 512 + l * 8 + 4);
    float o0[8], o1[8];
#pragma unroll
    for (int j = 0; j < 8; j++) {
        o0[j] = (f0[j] - mu) * rs * fg0[j] + fb0[j];
        o1[j] = (f1[j] - mu) * rs * fg1[j] + fb1[j];
    }
    *(uint4*)(xn + row * 1024 + l * 8) = pack8(o0);
    *(uint4*)(xn + row * 1024 + 512 + l * 8) = pack8(o1);
}

// ---------------------------------------------------------------- gemm8
#define FENCE asm volatile("" ::: "memory")
#define BARRIER do { FENCE; __builtin_amdgcn_s_barrier(); FENCE; } while (0)
#define WAIT_LGKM0 do { asm volatile("s_waitcnt lgkmcnt(0)" ::: "memory"); \
                        __builtin_amdgcn_sched_barrier(0); } while (0)
#define VMCNT(n) asm volatile("s_waitcnt vmcnt(" #n ")" ::: "memory")

#define SAp(buf) (LDSU + (buf) * 16384)
#define SBp(buf) (LDSU + 32768 + (buf) * 16384)

#define STG(gb, h, kcol, ldsreg) do { \
    const unsigned short* _g = (gb) + (size_t)((h) * 128) * 1024 + (kcol); \
    unsigned short* _d = (ldsreg) + ((h) * 128 + w * 8) * 64; \
    gld16(_g, _d); gld16(_g + 64 * 1024, _d + 64 * 64); } while (0)

#define LDA(buf, q, rfq, ks) (*(const bf16x8*)&SAp(buf)[ \
    (wm * 128 + (q) * 32 + (rfq) * 16 + (l & 15)) * 64 + ((((ks) * 32) + khi) ^ aswz)])
#define LDB(buf, cf, ks) (*(const bf16x8*)&SBp(buf)[ \
    (wn * 64 + (cf) * 16 + (l & 15)) * 64 + ((((ks) * 32) + khi) ^ aswz)])

#define MFMA_QUAD(q) do { \
    _Pragma("unroll") \
    for (int cf = 0; cf < 4; cf++) { \
        acc[(q)*2+0][cf] = __builtin_amdgcn_mfma_f32_16x16x32_bf16(aF00, bF[cf][0], acc[(q)*2+0][cf], 0, 0, 0); \
        acc[(q)*2+0][cf] = __builtin_amdgcn_mfma_f32_16x16x32_bf16(aF01, bF[cf][1], acc[(q)*2+0][cf], 0, 0, 0); \
        acc[(q)*2+1][cf] = __builtin_amdgcn_mfma_f32_16x16x32_bf16(aF10, bF[cf][0], acc[(q)*2+1][cf], 0, 0, 0); \
        acc[(q)*2+1][cf] = __builtin_amdgcn_mfma_f32_16x16x32_bf16(aF11, bF[cf][1], acc[(q)*2+1][cf], 0, 0, 0); \
    } } while (0)

#define PHASE(buf, q, STAGE_STMT, TAIL_STMT) do { \
    bf16x8 aF00 = LDA(buf, q, 0, 0), aF01 = LDA(buf, q, 0, 1); \
    bf16x8 aF10 = LDA(buf, q, 1, 0), aF11 = LDA(buf, q, 1, 1); \
    if ((q) == 0) { \
        _Pragma("unroll") \
        for (int cf = 0; cf < 4; cf++) { bF[cf][0] = LDB(buf, cf, 0); bF[cf][1] = LDB(buf, cf, 1); } \
    } \
    STAGE_STMT; \
    BARRIER; \
    WAIT_LGKM0; \
    __builtin_amdgcn_s_setprio(1); \
    MFMA_QUAD(q); \
    __builtin_amdgcn_s_setprio(0); \
    TAIL_STMT; \
    BARRIER; \
} while (0)

template <int MODE>
__global__ __launch_bounds__(512, 2) void gemm8(
    const unsigned short* __restrict__ A, const unsigned short* __restrict__ Bt,
    const float* __restrict__ bz0, const float* __restrict__ bz1,
    const float* __restrict__ bz2, const float* __restrict__ resid,
    void* __restrict__ outv, int NTL, size_t pstride)
{
    __shared__ __align__(16) unsigned short LDSU[65536];  // 128 KiB
    int cpx = gridDim.x >> 3;
    int bid = (blockIdx.x & 7) * cpx + (blockIdx.x >> 3);  // T1 XCD swizzle
    int mt = bid / NTL, ntl = bid % NTL;
    int m0 = mt * 256, n0 = ntl * 256;
    int tid = threadIdx.x, l = tid & 63, w = tid >> 6;
    int wm = w >> 2, wn = w & 3;
    int khi = (l >> 4) * 8;
    int aswz = (l & 7) * 8;

    const unsigned short* Ag = A + (size_t)(m0 + w * 8 + (l >> 3)) * 1024 + ((l & 7) ^ (l >> 3)) * 8;
    const unsigned short* Bg = Bt + (size_t)(n0 + w * 8 + (l >> 3)) * 1024 + ((l & 7) ^ (l >> 3)) * 8;
    unsigned short* sA0 = SAp(0);
    unsigned short* sA1 = SAp(1);
    unsigned short* sB0 = SBp(0);
    unsigned short* sB1 = SBp(1);

    f32x4 acc[8][4];
#pragma unroll
    for (int i = 0; i < 8; i++)
#pragma unroll
        for (int j = 0; j < 4; j++)
#pragma unroll
            for (int v = 0; v < 4; v++) acc[i][j][v] = 0.f;

    bf16x8 bF[4][2];

    // Prologue: A(0),B(0) -> buf0; B(1) -> buf1.
    STG(Ag, 0, 0, sA0); STG(Ag, 1, 0, sA0);
    STG(Bg, 0, 0, sB0); STG(Bg, 1, 0, sB0);
    STG(Bg, 0, 64, sB1); STG(Bg, 1, 64, sB1);
    VMCNT(4);
    BARRIER;

    for (int it = 0; it < 7; ++it) {
        int koff = it * 128;
        PHASE(0, 0, STG(Ag, 0, koff + 64, sA1), (void)0);
        PHASE(0, 1, STG(Ag, 1, koff + 64, sA1), (void)0);
        PHASE(0, 2, STG(Bg, 0, koff + 128, sB0), (void)0);
        PHASE(0, 3, STG(Bg, 1, koff + 128, sB0), VMCNT(4));
        PHASE(1, 0, STG(Ag, 0, koff + 128, sA0), (void)0);
        PHASE(1, 1, STG(Ag, 1, koff + 128, sA0), (void)0);
        PHASE(1, 2, STG(Bg, 0, koff + 192, sB1), (void)0);
        PHASE(1, 3, STG(Bg, 1, koff + 192, sB1), VMCNT(4));
    }
    PHASE(0, 0, STG(Ag, 0, 960, sA1), (void)0);
    PHASE(0, 1, STG(Ag, 1, 960, sA1), (void)0);
    PHASE(0, 2, (void)0, (void)0);
    PHASE(0, 3, (void)0, VMCNT(0));
    PHASE(1, 0, (void)0, (void)0);
    PHASE(1, 1, (void)0, (void)0);
    PHASE(1, 2, (void)0, (void)0);
    PHASE(1, 3, (void)0, (void)0);
    __builtin_amdgcn_sched_barrier(0);

    // ---------------- LDS-repack epilogues (coalesced wide stores) ----------
    if (MODE == 0) {
        unsigned short* Cs = LDSU;           // bf16 C[256][256], 16B-chunk XOR swizzle
        unsigned short* out = (unsigned short*)outv;
        int p = n0 >> 10;
        const float* bp = (p == 0) ? bz0 : (p == 1) ? bz1 : bz2;
        size_t pbase = (size_t)p * pstride;
        __syncthreads();
#pragma unroll
        for (int cf = 0; cf < 4; cf++) {
            int colc = wn * 64 + cf * 16 + (l & 15);
            int nn = ((n0 + colc) & 1023);
            float bias = bp[nn];
            int c8 = colc >> 3, ce = colc & 7;
#pragma unroll
            for (int rf = 0; rf < 8; rf++) {
#pragma unroll
                for (int v = 0; v < 4; v++) {
                    int rloc = wm * 128 + rf * 16 + (l >> 4) * 4 + v;
                    Cs[rloc * 256 + ((c8 ^ (rloc & 7)) << 3) + ce] =
                        f2bf(acc[rf][cf][v] + bias);
                }
            }
        }
        __syncthreads();
        int bg0 = m0 >> 5;
        int hg0 = (n0 & 1023) >> 6;
#pragma unroll
        for (int k = 0; k < 4; k++) {
            int pi = w * 4 + k;
            int b = pi >> 2, hh = pi & 3;
#pragma unroll
            for (int r4 = 0; r4 < 4; r4++) {
                int c = r4 * 64 + l;
                int s = c >> 3, d8 = c & 7;
                int row = b * 32 + s;
                int c8 = hh * 8 + d8;
                uint4 val = *(const uint4*)&Cs[row * 256 + ((c8 ^ (row & 7)) << 3)];
                size_t dst = pbase + (((size_t)((bg0 + b) * 16 + hg0 + hh) * 32 + s) << 6) + d8 * 8;
                *(uint4*)(out + dst) = val;
            }
        }
    } else {
        float* Cf = (float*)LDSU;            // f32 C[128][256], 16B-chunk XOR swizzle
        float* out = (float*)outv;
#pragma unroll
        for (int pass = 0; pass < 2; pass++) {
            __syncthreads();
#pragma unroll
            for (int rfq = 0; rfq < 4; rfq++) {
                int rf = pass * 4 + rfq;
#pragma unroll
                for (int cf = 0; cf < 4; cf++) {
                    int c0 = wn * 64 + cf * 16 + (l & 15);
                    int c4 = c0 >> 2, ce = c0 & 3;
#pragma unroll
                    for (int v = 0; v < 4; v++) {
                        int rl = wm * 64 + rfq * 16 + (l >> 4) * 4 + v;
                        Cf[rl * 256 + ((c4 ^ (rl & 7)) << 2) + ce] = acc[rf][cf][v];
                    }
                }
            }
            __syncthreads();
#pragma unroll
            for (int rep = 0; rep < 16; rep++) {
                int rr = rep * 8 + w;
                float4 val = *(const float4*)&Cf[rr * 256 + ((l ^ (rr & 7)) << 2)];
                int grow = m0 + (rr & 63) + ((rr >> 6) << 7) + pass * 64;
                int gcol = n0 + l * 4;
                float4 rz = *(const float4*)(resid + (size_t)grow * 1024 + gcol);
                float4 bzv = *(const float4*)(bz0 + gcol);
                float4 o;
                o.x = val.x + bzv.x + rz.x;
                o.y = val.y + bzv.y + rz.y;
                o.z = val.z + bzv.z + rz.z;
                o.w = val.w + bzv.w + rz.w;
                *(float4*)(out + (size_t)grow * 1024 + gcol) = o;
            }
        }
    }
}

// ---------------------------------------------------------------- attention
// 512 thr = 8 waves; each wave owns one (b_local, h). No barriers (per-wave LDS).
// QK^T and PV both via mfma_32x32x16_bf16. V staged transposed [dk][s] (pad 40),
// P staged bf16 [q][s] (pad 40) -> PV A/B frags are single aligned ds_read_b128.
__global__ __launch_bounds__(512) void attn_kernel(
    const unsigned short* __restrict__ qkv, const float* __restrict__ rb,
    unsigned short* __restrict__ ctx, size_t pstride)
{
    __shared__ unsigned short VT[8][64 * 40];
    __shared__ unsigned short Ps[8][32 * 40];
    int w8 = threadIdx.x >> 6, l = threadIdx.x & 63;
    int col = l & 31, hi = l >> 5;
    int bh = blockIdx.x * 8 + w8, h = bh & 15;
    size_t base = (size_t)bh << 11;
    const unsigned short* Qb = qkv + base;
    const unsigned short* Kb = Qb + pstride;
    const unsigned short* Vb = Kb + pstride;
    unsigned short* vt = VT[w8];
    unsigned short* ps = Ps[w8];

    // stage V^T (bf16): vt[dk][s]
#pragma unroll
    for (int r = 0; r < 4; r++) {
        int flat = r * 512 + l * 8;
        int s = flat >> 6, d0 = flat & 63;
        uint4 u = *(const uint4*)(Vb + flat);
        const unsigned short* e = (const unsigned short*)&u;
#pragma unroll
        for (int j = 0; j < 8; j++) vt[(d0 + j) * 40 + s] = e[j];
    }

    // QK^T
    f32x16 acc;
#pragma unroll
    for (int i = 0; i < 16; i++) acc[i] = 0.f;
#pragma unroll
    for (int t = 0; t < 4; t++) {
        bf16x8 aQ = *(const bf16x8*)(Qb + col * 64 + t * 16 + hi * 8);
        bf16x8 bK = *(const bf16x8*)(Kb + col * 64 + t * 16 + hi * 8);
        acc = __builtin_amdgcn_mfma_f32_32x32x16_bf16(aQ, bK, acc, 0, 0, 0);
    }

    // softmax -> ps (bf16). C/D row m = (r&3)+8*(r>>2)+4*hi, key col = l&31.
    const float* rbh = rb + h * 1024;
#pragma unroll
    for (int r = 0; r < 16; r++) {
        int m = (r & 3) + 8 * (r >> 2) + 4 * hi;
        float v = acc[r] * 0.125f + rbh[m * 32 + col];
        float mx = v;
#pragma unroll
        for (int msk = 1; msk < 32; msk <<= 1) mx = fmaxf(mx, __shfl_xor(mx, msk));
        float e = __expf(v - mx);
        float sm = e;
#pragma unroll
        for (int msk = 1; msk < 32; msk <<= 1) sm += __shfl_xor(sm, msk);
        ps[m * 40 + col] = f2bf(e / sm);
    }

    // PV: ctx[q][dk] = sum_s P[q][s] V[s][dk]; A=P rows, B=V^T rows.
    bf16x8 pa0 = *(const bf16x8*)&ps[(l & 31) * 40 + hi * 8];
    bf16x8 pa1 = *(const bf16x8*)&ps[(l & 31) * 40 + 16 + hi * 8];
    size_t rowb = (size_t)(bh >> 4) * 32;
#pragma unroll
    for (int c2 = 0; c2 < 2; c2++) {
        bf16x8 vb0 = *(const bf16x8*)&vt[(c2 * 32 + (l & 31)) * 40 + hi * 8];
        bf16x8 vb1 = *(const bf16x8*)&vt[(c2 * 32 + (l & 31)) * 40 + 16 + hi * 8];
        f32x16 o;
#pragma unroll
        for (int i = 0; i < 16; i++) o[i] = 0.f;
        o = __builtin_amdgcn_mfma_f32_32x32x16_bf16(pa0, vb0, o, 0, 0, 0);
        o = __builtin_amdgcn_mfma_f32_32x32x16_bf16(pa1, vb1, o, 0, 0, 0);
#pragma unroll
        for (int r = 0; r < 16; r++) {
            int m = (r & 3) + 8 * (r >> 2) + 4 * hi;
            ctx[(rowb + m) * 1024 + h * 64 + c2 * 32 + col] = f2bf(o[r]);
        }
    }
}

// ---------------------------------------------------------------- launch
extern "C" void kernel_launch(void* const* d_in, const int* in_sizes, int n_in,
                              void* d_out, int out_size, void* d_ws, size_t ws_size,
                              hipStream_t stream)
{
    const float* x  = (const float*)d_in[0];
    const float* lg = (const float*)d_in[1];
    const float* lb = (const float*)d_in[2];
    const float* wq = (const float*)d_in[3];
    const float* bq = (const float*)d_in[4];
    const float* wk = (const float*)d_in[5];
    const float* bk = (const float*)d_in[6];
    const float* wv = (const float*)d_in[7];
    const float* bv = (const float*)d_in[8];
    const float* wo = (const float*)d_in[9];
    const float* bo = (const float*)d_in[10];
    const float* rb = (const float*)d_in[11];
    float* out = (float*)d_out;
    unsigned short* ws = (unsigned short*)d_ws;

    unsigned short* wcatT = ws;                        // 3072*1024
    unsigned short* woT   = wcatT + 3145728;           // 1024*1024
    unsigned short* xnctx = woT + 1048576;             // 65536*1024 (xn -> ctx in place)
    unsigned short* qkvc  = xnctx + 67108864ull;       // QKV chunk buffer

    const size_t need4 = (3145728ull + 1048576ull + 67108864ull + 50331648ull) * 2;
    int nChunks  = (ws_size >= need4) ? 4 : 8;
    int rowsPer  = 65536 / nChunks;            // 16384 or 8192
    size_t pstr  = (size_t)rowsPer * 1024;

    transpose_w<<<dim3(1024), dim3(256), 0, stream>>>(wq, wk, wv, wo, wcatT, woT);
    ln_kernel<<<dim3(16384), dim3(256), 0, stream>>>(x, lg, lb, xnctx);

    int gemm0Grid = (rowsPer / 256) * 12;      // 768 or 384
    int attnGrid  = (rowsPer / 32) * 16 / 8;   // 8 bh per block

    for (int c = 0; c < nChunks; c++) {
        const unsigned short* Ac = xnctx + (size_t)c * pstr;
        unsigned short* ctxc = xnctx + (size_t)c * pstr;
        gemm8<0><<<dim3(gemm0Grid), dim3(512), 0, stream>>>(
            Ac, wcatT, bq, bk, bv, (const float*)nullptr, (void*)qkvc, 12, pstr);
        attn_kernel<<<dim3(attnGrid), dim3(512), 0, stream>>>(qkvc, rb, ctxc, pstr);
    }

    gemm8<1><<<dim3(1024), dim3(512), 0, stream>>>(
        xnctx, woT, bo, bo, bo, x, (void*)out, 4, 0);
}

// Round 6
// 785.001 us; speedup vs baseline: 1.4606x; 1.0177x over previous
//
#include <hip/hip_runtime.h>
#include <stdint.h>

// B=2048, S=32, D=1024, H=16, DK=64. d_in/d_out FLOAT32; internal bf16.
// Pipeline: transpose_w -> ln -> Nc x( gemm8<QKV chunk> -> attn ) -> gemm8<OUT>.
// gemm8: 256x256, BK=64, 8 waves, 8-phase counted-vmcnt (T1+T2+T3+T4+T5),
//        LDS-repack coalesced epilogues. attn: MFMA QK^T + MFMA PV, bf16 LDS.

typedef __attribute__((ext_vector_type(8))) short bf16x8;
typedef __attribute__((ext_vector_type(4))) float f32x4;
typedef __attribute__((ext_vector_type(16))) float f32x16;

__device__ __forceinline__ float bf2f(unsigned short u) {
    return __uint_as_float(((unsigned)u) << 16);
}
__device__ __forceinline__ unsigned short f2bf(float f) {
    unsigned u = __float_as_uint(f);
    u += 0x7FFFu + ((u >> 16) & 1u);
    return (unsigned short)(u >> 16);
}
__device__ __forceinline__ uint4 pack8(const float* f) {
    uint4 u;
    u.x = (unsigned)f2bf(f[0]) | ((unsigned)f2bf(f[1]) << 16);
    u.y = (unsigned)f2bf(f[2]) | ((unsigned)f2bf(f[3]) << 16);
    u.z = (unsigned)f2bf(f[4]) | ((unsigned)f2bf(f[5]) << 16);
    u.w = (unsigned)f2bf(f[6]) | ((unsigned)f2bf(f[7]) << 16);
    return u;
}

typedef __attribute__((address_space(3))) unsigned lds_u32;
typedef const __attribute__((address_space(1))) unsigned glb_u32;
__device__ __forceinline__ void gld16(const void* g, void* l) {
    __builtin_amdgcn_global_load_lds((glb_u32*)g, (lds_u32*)l, 16, 0, 0);
}

// ---------------------------------------------------------------- transpose
__global__ __launch_bounds__(256) void transpose_w(
    const float* __restrict__ wq, const float* __restrict__ wk,
    const float* __restrict__ wv, const float* __restrict__ wo,
    unsigned short* __restrict__ wcatT, unsigned short* __restrict__ woT)
{
    __shared__ unsigned short T[64 * 72];
    int bid = blockIdx.x;
    int p = bid >> 8;
    int t = bid & 255;
    int k0 = (t >> 4) * 64, n0 = (t & 15) * 64;
    const float* src = (p == 0) ? wq : (p == 1) ? wk : (p == 2) ? wv : wo;
    unsigned short* dst = (p < 3) ? (wcatT + (size_t)p * 1048576) : woT;
    int tid = threadIdx.x;
#pragma unroll
    for (int it = 0; it < 2; it++) {
        int flat = it * 2048 + tid * 8;
        int r = flat >> 6, c = flat & 63;
        const float* s4 = src + (size_t)(k0 + r) * 1024 + n0 + c;
        float4 u0 = *(const float4*)s4;
        float4 u1 = *(const float4*)(s4 + 4);
        float f[8] = {u0.x, u0.y, u0.z, u0.w, u1.x, u1.y, u1.z, u1.w};
        *(uint4*)&T[r * 72 + c] = pack8(f);
    }
    __syncthreads();
#pragma unroll
    for (int it = 0; it < 2; it++) {
        int flat = it * 2048 + tid * 8;
        int rn = flat >> 6, ck = flat & 63;
        unsigned short v[8];
#pragma unroll
        for (int j = 0; j < 8; j++) v[j] = T[(ck + j) * 72 + rn];
        uint4 u;
        u.x = (unsigned)v[0] | ((unsigned)v[1] << 16);
        u.y = (unsigned)v[2] | ((unsigned)v[3] << 16);
        u.z = (unsigned)v[4] | ((unsigned)v[5] << 16);
        u.w = (unsigned)v[6] | ((unsigned)v[7] << 16);
        *(uint4*)(dst + (size_t)(n0 + rn) * 1024 + k0 + ck) = u;
    }
}

// ---------------------------------------------------------------- layernorm
__global__ __launch_bounds__(256) void ln_kernel(
    const float* __restrict__ x, const float* __restrict__ gg,
    const float* __restrict__ bb, unsigned short* __restrict__ xn)
{
    int l = threadIdx.x & 63;
    size_t row = (size_t)blockIdx.x * 4 + (threadIdx.x >> 6);
    const float* xr = x + row * 1024;
    float f0[8], f1[8];
    *(float4*)&f0[0] = *(const float4*)(xr + l * 8);
    *(float4*)&f0[4] = *(const float4*)(xr + l * 8 + 4);
    *(float4*)&f1[0] = *(const float4*)(xr + 512 + l * 8);
    *(float4*)&f1[4] = *(const float4*)(xr + 512 + l * 8 + 4);
    float s = 0.f, s2 = 0.f;
#pragma unroll
    for (int j = 0; j < 8; j++) { s += f0[j] + f1[j]; s2 += f0[j] * f0[j] + f1[j] * f1[j]; }
#pragma unroll
    for (int m = 1; m < 64; m <<= 1) { s += __shfl_xor(s, m); s2 += __shfl_xor(s2, m); }
    float mu = s * (1.f / 1024.f);
    float var = s2 * (1.f / 1024.f) - mu * mu;
    float rs = rsqrtf(var + 1e-5f);
    float fg0[8], fg1[8], fb0[8], fb1[8];
    *(float4*)&fg0[0] = *(const float4*)(gg + l * 8);
    *(float4*)&fg0[4] = *(const float4*)(gg + l * 8 + 4);
    *(float4*)&fg1[0] = *(const float4*)(gg + 512 + l * 8);
    *(float4*)&fg1[4] = *(const float4*)(gg + 512 + l * 8 + 4);
    *(float4*)&fb0[0] = *(const float4*)(bb + l * 8);
    *(float4*)&fb0[4] = *(const float4*)(bb + l * 8 + 4);
    *(float4*)&fb1[0] = *(const float4*)(bb + 512 + l * 8);
    *(float4*)&fb1[4] = *(const float4*)(bb + 512 + l * 8 + 4);
    float o0[8], o1[8];
#pragma unroll
    for (int j = 0; j < 8; j++) {
        o0[j] = (f0[j] - mu) * rs * fg0[j] + fb0[j];
        o1[j] = (f1[j] - mu) * rs * fg1[j] + fb1[j];
    }
    *(uint4*)(xn + row * 1024 + l * 8) = pack8(o0);
    *(uint4*)(xn + row * 1024 + 512 + l * 8) = pack8(o1);
}

// ---------------------------------------------------------------- gemm8
#define FENCE asm volatile("" ::: "memory")
#define BARRIER do { FENCE; __builtin_amdgcn_s_barrier(); FENCE; } while (0)
#define WAIT_LGKM0 do { asm volatile("s_waitcnt lgkmcnt(0)" ::: "memory"); \
                        __builtin_amdgcn_sched_barrier(0); } while (0)
#define VMCNT(n) asm volatile("s_waitcnt vmcnt(" #n ")" ::: "memory")

#define SAp(buf) (LDSU + (buf) * 16384)
#define SBp(buf) (LDSU + 32768 + (buf) * 16384)

#define STG(gb, h, kcol, ldsreg) do { \
    const unsigned short* _g = (gb) + (size_t)((h) * 128) * 1024 + (kcol); \
    unsigned short* _d = (ldsreg) + ((h) * 128 + w * 8) * 64; \
    gld16(_g, _d); gld16(_g + 64 * 1024, _d + 64 * 64); } while (0)

#define LDA(buf, q, rfq, ks) (*(const bf16x8*)&SAp(buf)[ \
    (wm * 128 + (q) * 32 + (rfq) * 16 + (l & 15)) * 64 + ((((ks) * 32) + khi) ^ aswz)])
#define LDB(buf, cf, ks) (*(const bf16x8*)&SBp(buf)[ \
    (wn * 64 + (cf) * 16 + (l & 15)) * 64 + ((((ks) * 32) + khi) ^ aswz)])

#define MFMA_QUAD(q) do { \
    _Pragma("unroll") \
    for (int cf = 0; cf < 4; cf++) { \
        acc[(q)*2+0][cf] = __builtin_amdgcn_mfma_f32_16x16x32_bf16(aF00, bF[cf][0], acc[(q)*2+0][cf], 0, 0, 0); \
        acc[(q)*2+0][cf] = __builtin_amdgcn_mfma_f32_16x16x32_bf16(aF01, bF[cf][1], acc[(q)*2+0][cf], 0, 0, 0); \
        acc[(q)*2+1][cf] = __builtin_amdgcn_mfma_f32_16x16x32_bf16(aF10, bF[cf][0], acc[(q)*2+1][cf], 0, 0, 0); \
        acc[(q)*2+1][cf] = __builtin_amdgcn_mfma_f32_16x16x32_bf16(aF11, bF[cf][1], acc[(q)*2+1][cf], 0, 0, 0); \
    } } while (0)

#define PHASE(buf, q, STAGE_STMT, TAIL_STMT) do { \
    bf16x8 aF00 = LDA(buf, q, 0, 0), aF01 = LDA(buf, q, 0, 1); \
    bf16x8 aF10 = LDA(buf, q, 1, 0), aF11 = LDA(buf, q, 1, 1); \
    if ((q) == 0) { \
        _Pragma("unroll") \
        for (int cf = 0; cf < 4; cf++) { bF[cf][0] = LDB(buf, cf, 0); bF[cf][1] = LDB(buf, cf, 1); } \
    } \
    STAGE_STMT; \
    BARRIER; \
    WAIT_LGKM0; \
    __builtin_amdgcn_s_setprio(1); \
    MFMA_QUAD(q); \
    __builtin_amdgcn_s_setprio(0); \
    TAIL_STMT; \
    BARRIER; \
} while (0)

template <int MODE>
__global__ __launch_bounds__(512, 2) void gemm8(
    const unsigned short* __restrict__ A, const unsigned short* __restrict__ Bt,
    const float* __restrict__ bz0, const float* __restrict__ bz1,
    const float* __restrict__ bz2, const float* __restrict__ resid,
    void* __restrict__ outv, int NTL, size_t pstride)
{
    __shared__ __align__(16) unsigned short LDSU[65536];  // 128 KiB
    int cpx = gridDim.x >> 3;
    int bid = (blockIdx.x & 7) * cpx + (blockIdx.x >> 3);  // T1 XCD swizzle
    int mt = bid / NTL, ntl = bid % NTL;
    int m0 = mt * 256, n0 = ntl * 256;
    int tid = threadIdx.x, l = tid & 63, w = tid >> 6;
    int wm = w >> 2, wn = w & 3;
    int khi = (l >> 4) * 8;
    int aswz = (l & 7) * 8;

    const unsigned short* Ag = A + (size_t)(m0 + w * 8 + (l >> 3)) * 1024 + ((l & 7) ^ (l >> 3)) * 8;
    const unsigned short* Bg = Bt + (size_t)(n0 + w * 8 + (l >> 3)) * 1024 + ((l & 7) ^ (l >> 3)) * 8;
    unsigned short* sA0 = SAp(0);
    unsigned short* sA1 = SAp(1);
    unsigned short* sB0 = SBp(0);
    unsigned short* sB1 = SBp(1);

    f32x4 acc[8][4];
#pragma unroll
    for (int i = 0; i < 8; i++)
#pragma unroll
        for (int j = 0; j < 4; j++)
#pragma unroll
            for (int v = 0; v < 4; v++) acc[i][j][v] = 0.f;

    bf16x8 bF[4][2];

    // Prologue: A(0),B(0) -> buf0; B(1) -> buf1.
    STG(Ag, 0, 0, sA0); STG(Ag, 1, 0, sA0);
    STG(Bg, 0, 0, sB0); STG(Bg, 1, 0, sB0);
    STG(Bg, 0, 64, sB1); STG(Bg, 1, 64, sB1);
    VMCNT(4);
    BARRIER;

    for (int it = 0; it < 7; ++it) {
        int koff = it * 128;
        PHASE(0, 0, STG(Ag, 0, koff + 64, sA1), (void)0);
        PHASE(0, 1, STG(Ag, 1, koff + 64, sA1), (void)0);
        PHASE(0, 2, STG(Bg, 0, koff + 128, sB0), (void)0);
        PHASE(0, 3, STG(Bg, 1, koff + 128, sB0), VMCNT(4));
        PHASE(1, 0, STG(Ag, 0, koff + 128, sA0), (void)0);
        PHASE(1, 1, STG(Ag, 1, koff + 128, sA0), (void)0);
        PHASE(1, 2, STG(Bg, 0, koff + 192, sB1), (void)0);
        PHASE(1, 3, STG(Bg, 1, koff + 192, sB1), VMCNT(4));
    }
    PHASE(0, 0, STG(Ag, 0, 960, sA1), (void)0);
    PHASE(0, 1, STG(Ag, 1, 960, sA1), (void)0);
    PHASE(0, 2, (void)0, (void)0);
    PHASE(0, 3, (void)0, VMCNT(0));
    PHASE(1, 0, (void)0, (void)0);
    PHASE(1, 1, (void)0, (void)0);
    PHASE(1, 2, (void)0, (void)0);
    PHASE(1, 3, (void)0, (void)0);
    __builtin_amdgcn_sched_barrier(0);

    // ---------------- LDS-repack epilogues (coalesced wide stores) ----------
    if (MODE == 0) {
        unsigned short* Cs = LDSU;           // bf16 C[256][256], 16B-chunk XOR swizzle
        unsigned short* out = (unsigned short*)outv;
        int p = n0 >> 10;
        const float* bp = (p == 0) ? bz0 : (p == 1) ? bz1 : bz2;
        size_t pbase = (size_t)p * pstride;
        __syncthreads();
#pragma unroll
        for (int cf = 0; cf < 4; cf++) {
            int colc = wn * 64 + cf * 16 + (l & 15);
            int nn = ((n0 + colc) & 1023);
            float bias = bp[nn];
            int c8 = colc >> 3, ce = colc & 7;
#pragma unroll
            for (int rf = 0; rf < 8; rf++) {
#pragma unroll
                for (int v = 0; v < 4; v++) {
                    int rloc = wm * 128 + rf * 16 + (l >> 4) * 4 + v;
                    Cs[rloc * 256 + ((c8 ^ (rloc & 7)) << 3) + ce] =
                        f2bf(acc[rf][cf][v] + bias);
                }
            }
        }
        __syncthreads();
        int bg0 = m0 >> 5;
        int hg0 = (n0 & 1023) >> 6;
#pragma unroll
        for (int k = 0; k < 4; k++) {
            int pi = w * 4 + k;
            int b = pi >> 2, hh = pi & 3;
#pragma unroll
            for (int r4 = 0; r4 < 4; r4++) {
                int c = r4 * 64 + l;
                int s = c >> 3, d8 = c & 7;
                int row = b * 32 + s;
                int c8 = hh * 8 + d8;
                uint4 val = *(const uint4*)&Cs[row * 256 + ((c8 ^ (row & 7)) << 3)];
                size_t dst = pbase + (((size_t)((bg0 + b) * 16 + hg0 + hh) * 32 + s) << 6) + d8 * 8;
                *(uint4*)(out + dst) = val;
            }
        }
    } else {
        float* Cf = (float*)LDSU;            // f32 C[128][256], 16B-chunk XOR swizzle
        float* out = (float*)outv;
        int gcol = n0 + l * 4;               // lane-constant output column
        float4 bzv = *(const float4*)(bz0 + gcol);   // hoisted: 1 bias load total
#pragma unroll
        for (int pass = 0; pass < 2; pass++) {
            __syncthreads();
#pragma unroll
            for (int rfq = 0; rfq < 4; rfq++) {
                int rf = pass * 4 + rfq;
#pragma unroll
                for (int cf = 0; cf < 4; cf++) {
                    int c0 = wn * 64 + cf * 16 + (l & 15);
                    int c4 = c0 >> 2, ce = c0 & 3;
#pragma unroll
                    for (int v = 0; v < 4; v++) {
                        int rl = wm * 64 + rfq * 16 + (l >> 4) * 4 + v;
                        Cf[rl * 256 + ((c4 ^ (rl & 7)) << 2) + ce] = acc[rf][cf][v];
                    }
                }
            }
            __syncthreads();
#pragma unroll
            for (int rb4 = 0; rb4 < 4; rb4++) {   // 4 batches of 4 rows: prefetch resid
                float4 rz[4], cv[4];
#pragma unroll
                for (int k = 0; k < 4; k++) {
                    int rr = (rb4 * 4 + k) * 8 + w;
                    int grow = m0 + (rr & 63) + ((rr >> 6) << 7) + pass * 64;
                    rz[k] = *(const float4*)(resid + (size_t)grow * 1024 + gcol);
                }
#pragma unroll
                for (int k = 0; k < 4; k++) {
                    int rr = (rb4 * 4 + k) * 8 + w;
                    cv[k] = *(const float4*)&Cf[rr * 256 + ((l ^ (rr & 7)) << 2)];
                }
#pragma unroll
                for (int k = 0; k < 4; k++) {
                    int rr = (rb4 * 4 + k) * 8 + w;
                    int grow = m0 + (rr & 63) + ((rr >> 6) << 7) + pass * 64;
                    float4 o;
                    o.x = cv[k].x + bzv.x + rz[k].x;
                    o.y = cv[k].y + bzv.y + rz[k].y;
                    o.z = cv[k].z + bzv.z + rz[k].z;
                    o.w = cv[k].w + bzv.w + rz[k].w;
                    *(float4*)(out + (size_t)grow * 1024 + gcol) = o;
                }
            }
        }
    }
}

// ---------------------------------------------------------------- attention
// 512 thr = 8 waves; each wave owns one (b_local, h). No barriers (per-wave LDS).
__global__ __launch_bounds__(512) void attn_kernel(
    const unsigned short* __restrict__ qkv, const float* __restrict__ rb,
    unsigned short* __restrict__ ctx, size_t pstride)
{
    __shared__ unsigned short VT[8][64 * 40];
    __shared__ unsigned short Ps[8][32 * 40];
    int w8 = threadIdx.x >> 6, l = threadIdx.x & 63;
    int col = l & 31, hi = l >> 5;
    int bh = blockIdx.x * 8 + w8, h = bh & 15;
    size_t base = (size_t)bh << 11;
    const unsigned short* Qb = qkv + base;
    const unsigned short* Kb = Qb + pstride;
    const unsigned short* Vb = Kb + pstride;
    unsigned short* vt = VT[w8];
    unsigned short* ps = Ps[w8];

    // stage V^T (bf16): vt[dk][s]
#pragma unroll
    for (int r = 0; r < 4; r++) {
        int flat = r * 512 + l * 8;
        int s = flat >> 6, d0 = flat & 63;
        uint4 u = *(const uint4*)(Vb + flat);
        const unsigned short* e = (const unsigned short*)&u;
#pragma unroll
        for (int j = 0; j < 8; j++) vt[(d0 + j) * 40 + s] = e[j];
    }

    // QK^T
    f32x16 acc;
#pragma unroll
    for (int i = 0; i < 16; i++) acc[i] = 0.f;
#pragma unroll
    for (int t = 0; t < 4; t++) {
        bf16x8 aQ = *(const bf16x8*)(Qb + col * 64 + t * 16 + hi * 8);
        bf16x8 bK = *(const bf16x8*)(Kb + col * 64 + t * 16 + hi * 8);
        acc = __builtin_amdgcn_mfma_f32_32x32x16_bf16(aQ, bK, acc, 0, 0, 0);
    }

    // softmax -> ps (bf16). C/D row m = (r&3)+8*(r>>2)+4*hi, key col = l&31.
    const float* rbh = rb + h * 1024;
#pragma unroll
    for (int r = 0; r < 16; r++) {
        int m = (r & 3) + 8 * (r >> 2) + 4 * hi;
        float v = acc[r] * 0.125f + rbh[m * 32 + col];
        float mx = v;
#pragma unroll
        for (int msk = 1; msk < 32; msk <<= 1) mx = fmaxf(mx, __shfl_xor(mx, msk));
        float e = __expf(v - mx);
        float sm = e;
#pragma unroll
        for (int msk = 1; msk < 32; msk <<= 1) sm += __shfl_xor(sm, msk);
        ps[m * 40 + col] = f2bf(e / sm);
    }

    // PV: ctx[q][dk] = sum_s P[q][s] V[s][dk]; A=P rows, B=V^T rows.
    bf16x8 pa0 = *(const bf16x8*)&ps[(l & 31) * 40 + hi * 8];
    bf16x8 pa1 = *(const bf16x8*)&ps[(l & 31) * 40 + 16 + hi * 8];
    size_t rowb = (size_t)(bh >> 4) * 32;
#pragma unroll
    for (int c2 = 0; c2 < 2; c2++) {
        bf16x8 vb0 = *(const bf16x8*)&vt[(c2 * 32 + (l & 31)) * 40 + hi * 8];
        bf16x8 vb1 = *(const bf16x8*)&vt[(c2 * 32 + (l & 31)) * 40 + 16 + hi * 8];
        f32x16 o;
#pragma unroll
        for (int i = 0; i < 16; i++) o[i] = 0.f;
        o = __builtin_amdgcn_mfma_f32_32x32x16_bf16(pa0, vb0, o, 0, 0, 0);
        o = __builtin_amdgcn_mfma_f32_32x32x16_bf16(pa1, vb1, o, 0, 0, 0);
#pragma unroll
        for (int r = 0; r < 16; r++) {
            int m = (r & 3) + 8 * (r >> 2) + 4 * hi;
            ctx[(rowb + m) * 1024 + h * 64 + c2 * 32 + col] = f2bf(o[r]);
        }
    }
}

// ---------------------------------------------------------------- launch
extern "C" void kernel_launch(void* const* d_in, const int* in_sizes, int n_in,
                              void* d_out, int out_size, void* d_ws, size_t ws_size,
                              hipStream_t stream)
{
    const float* x  = (const float*)d_in[0];
    const float* lg = (const float*)d_in[1];
    const float* lb = (const float*)d_in[2];
    const float* wq = (const float*)d_in[3];
    const float* bq = (const float*)d_in[4];
    const float* wk = (const float*)d_in[5];
    const float* bk = (const float*)d_in[6];
    const float* wv = (const float*)d_in[7];
    const float* bv = (const float*)d_in[8];
    const float* wo = (const float*)d_in[9];
    const float* bo = (const float*)d_in[10];
    const float* rb = (const float*)d_in[11];
    float* out = (float*)d_out;
    unsigned short* ws = (unsigned short*)d_ws;

    unsigned short* wcatT = ws;                        // 3072*1024
    unsigned short* woT   = wcatT + 3145728;           // 1024*1024
    unsigned short* xnctx = woT + 1048576;             // 65536*1024 (xn -> ctx in place)
    unsigned short* qkvc  = xnctx + 67108864ull;       // QKV (chunk) buffer

    const size_t elems_fixed = 3145728ull + 1048576ull + 67108864ull;
    const size_t need1 = (elems_fixed + 201326592ull) * 2;   // full QKV: ~545 MB
    const size_t need4 = (elems_fixed + 50331648ull) * 2;    // 4 chunks: ~244 MB
    int nChunks = (ws_size >= need1) ? 1 : (ws_size >= need4) ? 4 : 8;
    int rowsPer = 65536 / nChunks;             // 65536 / 16384 / 8192
    size_t pstr = (size_t)rowsPer * 1024;

    transpose_w<<<dim3(1024), dim3(256), 0, stream>>>(wq, wk, wv, wo, wcatT, woT);
    ln_kernel<<<dim3(16384), dim3(256), 0, stream>>>(x, lg, lb, xnctx);

    int gemm0Grid = (rowsPer / 256) * 12;      // 3072 / 768 / 384 (multiple of 8)
    int attnGrid  = rowsPer / 16;              // 4096 / 1024 / 512

    for (int c = 0; c < nChunks; c++) {
        const unsigned short* Ac = xnctx + (size_t)c * pstr;
        unsigned short* ctxc = xnctx + (size_t)c * pstr;
        gemm8<0><<<dim3(gemm0Grid), dim3(512), 0, stream>>>(
            Ac, wcatT, bq, bk, bv, (const float*)nullptr, (void*)qkvc, 12, pstr);
        attn_kernel<<<dim3(attnGrid), dim3(512), 0, stream>>>(qkvc, rb, ctxc, pstr);
    }

    gemm8<1><<<dim3(1024), dim3(512), 0, stream>>>(
        xnctx, woT, bo, bo, bo, x, (void*)out, 4, 0);
}

// Round 7
// 782.096 us; speedup vs baseline: 1.4660x; 1.0037x over previous
//
#include <hip/hip_runtime.h>
#include <stdint.h>

// B=2048, S=32, D=1024, H=16, DK=64. d_in/d_out FLOAT32; internal bf16.
// Pipeline: transpose_w -> ln -> fqa (QKV-GEMM + attention fused) -> gemm8<out>.
// fqa: BM=256 x BN=192 (Q|K|V 64-col slices of one head), BK=64, 8 waves,
//      8-phase counted-vmcnt loop, then in-LDS attention per batch, ctx direct.

typedef __attribute__((ext_vector_type(8))) short bf16x8;
typedef __attribute__((ext_vector_type(4))) float f32x4;
typedef __attribute__((ext_vector_type(16))) float f32x16;

__device__ __forceinline__ float bf2f(unsigned short u) {
    return __uint_as_float(((unsigned)u) << 16);
}
__device__ __forceinline__ unsigned short f2bf(float f) {
    unsigned u = __float_as_uint(f);
    u += 0x7FFFu + ((u >> 16) & 1u);
    return (unsigned short)(u >> 16);
}
__device__ __forceinline__ uint4 pack8(const float* f) {
    uint4 u;
    u.x = (unsigned)f2bf(f[0]) | ((unsigned)f2bf(f[1]) << 16);
    u.y = (unsigned)f2bf(f[2]) | ((unsigned)f2bf(f[3]) << 16);
    u.z = (unsigned)f2bf(f[4]) | ((unsigned)f2bf(f[5]) << 16);
    u.w = (unsigned)f2bf(f[6]) | ((unsigned)f2bf(f[7]) << 16);
    return u;
}

typedef __attribute__((address_space(3))) unsigned lds_u32;
typedef const __attribute__((address_space(1))) unsigned glb_u32;
__device__ __forceinline__ void gld16(const void* g, void* l) {
    __builtin_amdgcn_global_load_lds((glb_u32*)g, (lds_u32*)l, 16, 0, 0);
}

// ---------------------------------------------------------------- transpose
__global__ __launch_bounds__(256) void transpose_w(
    const float* __restrict__ wq, const float* __restrict__ wk,
    const float* __restrict__ wv, const float* __restrict__ wo,
    unsigned short* __restrict__ wcatT, unsigned short* __restrict__ woT)
{
    __shared__ unsigned short T[64 * 72];
    int bid = blockIdx.x;
    int p = bid >> 8;
    int t = bid & 255;
    int k0 = (t >> 4) * 64, n0 = (t & 15) * 64;
    const float* src = (p == 0) ? wq : (p == 1) ? wk : (p == 2) ? wv : wo;
    unsigned short* dst = (p < 3) ? (wcatT + (size_t)p * 1048576) : woT;
    int tid = threadIdx.x;
#pragma unroll
    for (int it = 0; it < 2; it++) {
        int flat = it * 2048 + tid * 8;
        int r = flat >> 6, c = flat & 63;
        const float* s4 = src + (size_t)(k0 + r) * 1024 + n0 + c;
        float4 u0 = *(const float4*)s4;
        float4 u1 = *(const float4*)(s4 + 4);
        float f[8] = {u0.x, u0.y, u0.z, u0.w, u1.x, u1.y, u1.z, u1.w};
        *(uint4*)&T[r * 72 + c] = pack8(f);
    }
    __syncthreads();
#pragma unroll
    for (int it = 0; it < 2; it++) {
        int flat = it * 2048 + tid * 8;
        int rn = flat >> 6, ck = flat & 63;
        unsigned short v[8];
#pragma unroll
        for (int j = 0; j < 8; j++) v[j] = T[(ck + j) * 72 + rn];
        uint4 u;
        u.x = (unsigned)v[0] | ((unsigned)v[1] << 16);
        u.y = (unsigned)v[2] | ((unsigned)v[3] << 16);
        u.z = (unsigned)v[4] | ((unsigned)v[5] << 16);
        u.w = (unsigned)v[6] | ((unsigned)v[7] << 16);
        *(uint4*)(dst + (size_t)(n0 + rn) * 1024 + k0 + ck) = u;
    }
}

// ---------------------------------------------------------------- layernorm
__global__ __launch_bounds__(256) void ln_kernel(
    const float* __restrict__ x, const float* __restrict__ gg,
    const float* __restrict__ bb, unsigned short* __restrict__ xn)
{
    int l = threadIdx.x & 63;
    size_t row = (size_t)blockIdx.x * 4 + (threadIdx.x >> 6);
    const float* xr = x + row * 1024;
    float f0[8], f1[8];
    *(float4*)&f0[0] = *(const float4*)(xr + l * 8);
    *(float4*)&f0[4] = *(const float4*)(xr + l * 8 + 4);
    *(float4*)&f1[0] = *(const float4*)(xr + 512 + l * 8);
    *(float4*)&f1[4] = *(const float4*)(xr + 512 + l * 8 + 4);
    float s = 0.f, s2 = 0.f;
#pragma unroll
    for (int j = 0; j < 8; j++) { s += f0[j] + f1[j]; s2 += f0[j] * f0[j] + f1[j] * f1[j]; }
#pragma unroll
    for (int m = 1; m < 64; m <<= 1) { s += __shfl_xor(s, m); s2 += __shfl_xor(s2, m); }
    float mu = s * (1.f / 1024.f);
    float var = s2 * (1.f / 1024.f) - mu * mu;
    float rs = rsqrtf(var + 1e-5f);
    float fg0[8], fg1[8], fb0[8], fb1[8];
    *(float4*)&fg0[0] = *(const float4*)(gg + l * 8);
    *(float4*)&fg0[4] = *(const float4*)(gg + l * 8 + 4);
    *(float4*)&fg1[0] = *(const float4*)(gg + 512 + l * 8);
    *(float4*)&fg1[4] = *(const float4*)(gg + 512 + l * 8 + 4);
    *(float4*)&fb0[0] = *(const float4*)(bb + l * 8);
    *(float4*)&fb0[4] = *(const float4*)(bb + l * 8 + 4);
    *(float4*)&fb1[0] = *(const float4*)(bb + 512 + l * 8);
    *(float4*)&fb1[4] = *(const float4*)(bb + 512 + l * 8 + 4);
    float o0[8], o1[8];
#pragma unroll
    for (int j = 0; j < 8; j++) {
        o0[j] = (f0[j] - mu) * rs * fg0[j] + fb0[j];
        o1[j] = (f1[j] - mu) * rs * fg1[j] + fb1[j];
    }
    *(uint4*)(xn + row * 1024 + l * 8) = pack8(o0);
    *(uint4*)(xn + row * 1024 + 512 + l * 8) = pack8(o1);
}

// ---------------------------------------------------------------- common asm helpers
#define FENCE asm volatile("" ::: "memory")
#define BARRIER do { FENCE; __builtin_amdgcn_s_barrier(); FENCE; } while (0)
#define WAIT_LGKM0 do { asm volatile("s_waitcnt lgkmcnt(0)" ::: "memory"); \
                        __builtin_amdgcn_sched_barrier(0); } while (0)
#define VMCNT(n) asm volatile("s_waitcnt vmcnt(" #n ")" ::: "memory")

// ================================================================ fqa
// Fused QKV projection + attention. Block = 256 A-rows (8 batches) x 1 head.
// Loop LDS: A dbuf 2x[256][64], B dbuf 2x[192][64] (rows = Q|K|V 64-slices).
// Attn LDS (post-loop reuse): Q[256][72], K[256][72], VT[8][64][40], Ps[8][32][40].
#define FQ_SA(buf) (LDSU + (buf) * 16384)
#define FQ_SB(buf) (LDSU + 32768 + (buf) * 12288)
#define QS_OFF 0
#define KS_OFF 18432
#define VT_OFF 36864
#define PS_OFF 57344

#define ASTG(buf, g, koff) gld16(Ag + (size_t)(g) * 65536 + (koff), FQ_SA(buf) + ((g) * 64 + w * 8) * 64)
#define BSTG(buf, p, koff) gld16(((p) == 0 ? Bgq : (p) == 1 ? Bgk : Bgv) + (koff), \
                                 FQ_SB(buf) + ((p) * 64 + w * 8) * 64)

#define FLDA(buf, q, rfq, ks) (*(const bf16x8*)&FQ_SA(buf)[ \
    (wm * 128 + (q) * 32 + (rfq) * 16 + (l & 15)) * 64 + ((((ks) * 32) + khi) ^ aswz)])
#define FLDB(buf, cf, ks) (*(const bf16x8*)&FQ_SB(buf)[ \
    (wn * 48 + (cf) * 16 + (l & 15)) * 64 + ((((ks) * 32) + khi) ^ aswz)])

#define MFMA_TRI(q) do { \
    _Pragma("unroll") \
    for (int cf = 0; cf < 3; cf++) { \
        acc[(q)*2+0][cf] = __builtin_amdgcn_mfma_f32_16x16x32_bf16(aF00, bF[cf][0], acc[(q)*2+0][cf], 0, 0, 0); \
        acc[(q)*2+0][cf] = __builtin_amdgcn_mfma_f32_16x16x32_bf16(aF01, bF[cf][1], acc[(q)*2+0][cf], 0, 0, 0); \
        acc[(q)*2+1][cf] = __builtin_amdgcn_mfma_f32_16x16x32_bf16(aF10, bF[cf][0], acc[(q)*2+1][cf], 0, 0, 0); \
        acc[(q)*2+1][cf] = __builtin_amdgcn_mfma_f32_16x16x32_bf16(aF11, bF[cf][1], acc[(q)*2+1][cf], 0, 0, 0); \
    } } while (0)

#define FPHASE(buf, q, STAGE_STMT, TAIL_STMT) do { \
    bf16x8 aF00 = FLDA(buf, q, 0, 0), aF01 = FLDA(buf, q, 0, 1); \
    bf16x8 aF10 = FLDA(buf, q, 1, 0), aF11 = FLDA(buf, q, 1, 1); \
    if ((q) == 0) { \
        _Pragma("unroll") \
        for (int cf = 0; cf < 3; cf++) { bF[cf][0] = FLDB(buf, cf, 0); bF[cf][1] = FLDB(buf, cf, 1); } \
    } \
    STAGE_STMT; \
    BARRIER; \
    WAIT_LGKM0; \
    __builtin_amdgcn_s_setprio(1); \
    MFMA_TRI(q); \
    __builtin_amdgcn_s_setprio(0); \
    TAIL_STMT; \
    BARRIER; \
} while (0)

__global__ __launch_bounds__(512, 1) void fqa_kernel(
    const unsigned short* __restrict__ A, const unsigned short* __restrict__ wcatT,
    const float* __restrict__ bq, const float* __restrict__ bk,
    const float* __restrict__ bv, const float* __restrict__ rb,
    unsigned short* __restrict__ ctx)
{
    __shared__ __align__(16) unsigned short LDSU[67584];  // 132 KiB
    int cpx = gridDim.x >> 3;
    int bid = (blockIdx.x & 7) * cpx + (blockIdx.x >> 3);  // XCD swizzle: 16 head-blocks/panel XCD-local
    int mp = bid >> 4, h = bid & 15;
    int m0 = mp * 256;
    int tid = threadIdx.x, l = tid & 63, w = tid >> 6;
    int wm = w >> 2, wn = w & 3;
    int khi = (l >> 4) * 8;
    int aswz = (l & 7) * 8;
    int swzc = ((l & 7) ^ (l >> 3)) * 8;

    const unsigned short* Ag  = A + (size_t)(m0 + w * 8 + (l >> 3)) * 1024 + swzc;
    const unsigned short* Bgq = wcatT + (size_t)(h * 64 + w * 8 + (l >> 3)) * 1024 + swzc;
    const unsigned short* Bgk = Bgq + 1048576ull;
    const unsigned short* Bgv = Bgq + 2097152ull;

    f32x4 acc[8][3];
#pragma unroll
    for (int i = 0; i < 8; i++)
#pragma unroll
        for (int j = 0; j < 3; j++)
#pragma unroll
            for (int v = 0; v < 4; v++) acc[i][j][v] = 0.f;

    bf16x8 bF[3][2];

    // Prologue: A(0),B(0) -> buf0; B(1) -> buf1.
    ASTG(0, 0, 0); ASTG(0, 1, 0); ASTG(0, 2, 0); ASTG(0, 3, 0);
    BSTG(0, 0, 0); BSTG(0, 1, 0); BSTG(0, 2, 0);
    BSTG(1, 0, 64); BSTG(1, 1, 64); BSTG(1, 2, 64);
    VMCNT(3);
    BARRIER;

    for (int it = 0; it < 7; ++it) {
        int ko1 = (2 * it + 1) * 64, ko2 = (2 * it + 2) * 64, ko3 = (2 * it + 3) * 64;
        FPHASE(0, 0, do { ASTG(1, 0, ko1); ASTG(1, 1, ko1); } while (0), (void)0);
        FPHASE(0, 1, do { ASTG(1, 2, ko1); ASTG(1, 3, ko1); } while (0), (void)0);
        FPHASE(0, 2, do { BSTG(0, 0, ko2); BSTG(0, 1, ko2); } while (0), (void)0);
        FPHASE(0, 3, BSTG(0, 2, ko2), VMCNT(3));
        FPHASE(1, 0, do { ASTG(0, 0, ko2); ASTG(0, 1, ko2); } while (0), (void)0);
        FPHASE(1, 1, do { ASTG(0, 2, ko2); ASTG(0, 3, ko2); } while (0), (void)0);
        FPHASE(1, 2, do { BSTG(1, 0, ko3); BSTG(1, 1, ko3); } while (0), (void)0);
        FPHASE(1, 3, BSTG(1, 2, ko3), VMCNT(3));
    }
    // Final tiles 14 (buf0), 15 (buf1): only A(15) left to stage.
    FPHASE(0, 0, do { ASTG(1, 0, 960); ASTG(1, 1, 960); } while (0), (void)0);
    FPHASE(0, 1, do { ASTG(1, 2, 960); ASTG(1, 3, 960); } while (0), (void)0);
    FPHASE(0, 2, (void)0, (void)0);
    FPHASE(0, 3, (void)0, VMCNT(0));
    FPHASE(1, 0, (void)0, (void)0);
    FPHASE(1, 1, (void)0, (void)0);
    FPHASE(1, 2, (void)0, (void)0);
    FPHASE(1, 3, (void)0, (void)0);
    __builtin_amdgcn_sched_barrier(0);

    // ---- repack acc -> LDS: Q[256][72], K[256][72], VT[8][64][40] (bias fused)
#pragma unroll
    for (int cf = 0; cf < 3; cf++) {
        int seg = (wn * 3 + cf) >> 2;              // wave-uniform: 0=Q,1=K,2=V
        int cseg = wn * 48 + cf * 16 + (l & 15) - (seg << 6);
        const float* bp = (seg == 0) ? bq : (seg == 1) ? bk : bv;
        float bias = bp[h * 64 + cseg];
#pragma unroll
        for (int ai = 0; ai < 8; ai++) {
#pragma unroll
            for (int v = 0; v < 4; v++) {
                int row = wm * 128 + ai * 16 + (l >> 4) * 4 + v;  // b*32+s
                unsigned short val = f2bf(acc[ai][cf][v] + bias);
                if (seg == 0)      LDSU[QS_OFF + row * 72 + cseg] = val;
                else if (seg == 1) LDSU[KS_OFF + row * 72 + cseg] = val;
                else               LDSU[VT_OFF + (((row >> 5) << 6) + cseg) * 40 + (row & 31)] = val;
            }
        }
    }
    __syncthreads();

    // ---- in-LDS attention: wave w handles batch b=w
    {
        int col = l & 31, hi = l >> 5;
        f32x16 s;
#pragma unroll
        for (int i = 0; i < 16; i++) s[i] = 0.f;
#pragma unroll
        for (int t = 0; t < 4; t++) {
            bf16x8 aQ = *(const bf16x8*)&LDSU[QS_OFF + (w * 32 + col) * 72 + t * 16 + hi * 8];
            bf16x8 bK = *(const bf16x8*)&LDSU[KS_OFF + (w * 32 + col) * 72 + t * 16 + hi * 8];
            s = __builtin_amdgcn_mfma_f32_32x32x16_bf16(aQ, bK, s, 0, 0, 0);
        }
        const float* rbh = rb + h * 1024;
        unsigned short* ps = LDSU + PS_OFF + w * 1280;
#pragma unroll
        for (int r = 0; r < 16; r++) {
            int m = (r & 3) + 8 * (r >> 2) + 4 * hi;
            float v = s[r] * 0.125f + rbh[m * 32 + col];
            float mx = v;
#pragma unroll
            for (int msk = 1; msk < 32; msk <<= 1) mx = fmaxf(mx, __shfl_xor(mx, msk));
            float e = __expf(v - mx);
            float sm = e;
#pragma unroll
            for (int msk = 1; msk < 32; msk <<= 1) sm += __shfl_xor(sm, msk);
            ps[m * 40 + col] = f2bf(e / sm);
        }
        bf16x8 pa0 = *(const bf16x8*)&ps[col * 40 + hi * 8];
        bf16x8 pa1 = *(const bf16x8*)&ps[col * 40 + 16 + hi * 8];
        size_t rowb = ((size_t)mp * 8 + w) * 32;
#pragma unroll
        for (int c2 = 0; c2 < 2; c2++) {
            bf16x8 vb0 = *(const bf16x8*)&LDSU[VT_OFF + (w * 64 + c2 * 32 + col) * 40 + hi * 8];
            bf16x8 vb1 = *(const bf16x8*)&LDSU[VT_OFF + (w * 64 + c2 * 32 + col) * 40 + 16 + hi * 8];
            f32x16 o;
#pragma unroll
            for (int i = 0; i < 16; i++) o[i] = 0.f;
            o = __builtin_amdgcn_mfma_f32_32x32x16_bf16(pa0, vb0, o, 0, 0, 0);
            o = __builtin_amdgcn_mfma_f32_32x32x16_bf16(pa1, vb1, o, 0, 0, 0);
#pragma unroll
            for (int r = 0; r < 16; r++) {
                int m = (r & 3) + 8 * (r >> 2) + 4 * hi;
                ctx[(rowb + m) * 1024 + h * 64 + c2 * 32 + col] = f2bf(o[r]);
            }
        }
    }
}

// ================================================================ gemm8 (output proj + residual)
#define SAp(buf) (LDSU + (buf) * 16384)
#define SBp(buf) (LDSU + 32768 + (buf) * 16384)

#define STG(gb, hh, kcol, ldsreg) do { \
    const unsigned short* _g = (gb) + (size_t)((hh) * 128) * 1024 + (kcol); \
    unsigned short* _d = (ldsreg) + ((hh) * 128 + w * 8) * 64; \
    gld16(_g, _d); gld16(_g + 64 * 1024, _d + 64 * 64); } while (0)

#define LDA(buf, q, rfq, ks) (*(const bf16x8*)&SAp(buf)[ \
    (wm * 128 + (q) * 32 + (rfq) * 16 + (l & 15)) * 64 + ((((ks) * 32) + khi) ^ aswz)])
#define LDB(buf, cf, ks) (*(const bf16x8*)&SBp(buf)[ \
    (wn * 64 + (cf) * 16 + (l & 15)) * 64 + ((((ks) * 32) + khi) ^ aswz)])

#define MFMA_QUAD(q) do { \
    _Pragma("unroll") \
    for (int cf = 0; cf < 4; cf++) { \
        acc[(q)*2+0][cf] = __builtin_amdgcn_mfma_f32_16x16x32_bf16(aF00, bF[cf][0], acc[(q)*2+0][cf], 0, 0, 0); \
        acc[(q)*2+0][cf] = __builtin_amdgcn_mfma_f32_16x16x32_bf16(aF01, bF[cf][1], acc[(q)*2+0][cf], 0, 0, 0); \
        acc[(q)*2+1][cf] = __builtin_amdgcn_mfma_f32_16x16x32_bf16(aF10, bF[cf][0], acc[(q)*2+1][cf], 0, 0, 0); \
        acc[(q)*2+1][cf] = __builtin_amdgcn_mfma_f32_16x16x32_bf16(aF11, bF[cf][1], acc[(q)*2+1][cf], 0, 0, 0); \
    } } while (0)

#define PHASE(buf, q, STAGE_STMT, TAIL_STMT) do { \
    bf16x8 aF00 = LDA(buf, q, 0, 0), aF01 = LDA(buf, q, 0, 1); \
    bf16x8 aF10 = LDA(buf, q, 1, 0), aF11 = LDA(buf, q, 1, 1); \
    if ((q) == 0) { \
        _Pragma("unroll") \
        for (int cf = 0; cf < 4; cf++) { bF[cf][0] = LDB(buf, cf, 0); bF[cf][1] = LDB(buf, cf, 1); } \
    } \
    STAGE_STMT; \
    BARRIER; \
    WAIT_LGKM0; \
    __builtin_amdgcn_s_setprio(1); \
    MFMA_QUAD(q); \
    __builtin_amdgcn_s_setprio(0); \
    TAIL_STMT; \
    BARRIER; \
} while (0)

__global__ __launch_bounds__(512, 2) void gemm8res(
    const unsigned short* __restrict__ A, const unsigned short* __restrict__ Bt,
    const float* __restrict__ bz0, const float* __restrict__ resid,
    float* __restrict__ out, int NTL)
{
    __shared__ __align__(16) unsigned short LDSU[65536];  // 128 KiB
    int cpx = gridDim.x >> 3;
    int bid = (blockIdx.x & 7) * cpx + (blockIdx.x >> 3);
    int mt = bid / NTL, ntl = bid % NTL;
    int m0 = mt * 256, n0 = ntl * 256;
    int tid = threadIdx.x, l = tid & 63, w = tid >> 6;
    int wm = w >> 2, wn = w & 3;
    int khi = (l >> 4) * 8;
    int aswz = (l & 7) * 8;

    const unsigned short* Ag = A + (size_t)(m0 + w * 8 + (l >> 3)) * 1024 + ((l & 7) ^ (l >> 3)) * 8;
    const unsigned short* Bg = Bt + (size_t)(n0 + w * 8 + (l >> 3)) * 1024 + ((l & 7) ^ (l >> 3)) * 8;
    unsigned short* sA0 = SAp(0);
    unsigned short* sA1 = SAp(1);
    unsigned short* sB0 = SBp(0);
    unsigned short* sB1 = SBp(1);

    f32x4 acc[8][4];
#pragma unroll
    for (int i = 0; i < 8; i++)
#pragma unroll
        for (int j = 0; j < 4; j++)
#pragma unroll
            for (int v = 0; v < 4; v++) acc[i][j][v] = 0.f;

    bf16x8 bF[4][2];

    STG(Ag, 0, 0, sA0); STG(Ag, 1, 0, sA0);
    STG(Bg, 0, 0, sB0); STG(Bg, 1, 0, sB0);
    STG(Bg, 0, 64, sB1); STG(Bg, 1, 64, sB1);
    VMCNT(4);
    BARRIER;

    for (int it = 0; it < 7; ++it) {
        int koff = it * 128;
        PHASE(0, 0, STG(Ag, 0, koff + 64, sA1), (void)0);
        PHASE(0, 1, STG(Ag, 1, koff + 64, sA1), (void)0);
        PHASE(0, 2, STG(Bg, 0, koff + 128, sB0), (void)0);
        PHASE(0, 3, STG(Bg, 1, koff + 128, sB0), VMCNT(4));
        PHASE(1, 0, STG(Ag, 0, koff + 128, sA0), (void)0);
        PHASE(1, 1, STG(Ag, 1, koff + 128, sA0), (void)0);
        PHASE(1, 2, STG(Bg, 0, koff + 192, sB1), (void)0);
        PHASE(1, 3, STG(Bg, 1, koff + 192, sB1), VMCNT(4));
    }
    PHASE(0, 0, STG(Ag, 0, 960, sA1), (void)0);
    PHASE(0, 1, STG(Ag, 1, 960, sA1), (void)0);
    PHASE(0, 2, (void)0, (void)0);
    PHASE(0, 3, (void)0, VMCNT(0));
    PHASE(1, 0, (void)0, (void)0);
    PHASE(1, 1, (void)0, (void)0);
    PHASE(1, 2, (void)0, (void)0);
    PHASE(1, 3, (void)0, (void)0);
    __builtin_amdgcn_sched_barrier(0);

    // LDS-repack f32 epilogue: + bias + residual, coalesced float4 I/O.
    float* Cf = (float*)LDSU;
    int gcol = n0 + l * 4;
    float4 bzv = *(const float4*)(bz0 + gcol);
#pragma unroll
    for (int pass = 0; pass < 2; pass++) {
        __syncthreads();
#pragma unroll
        for (int rfq = 0; rfq < 4; rfq++) {
            int rf = pass * 4 + rfq;
#pragma unroll
            for (int cf = 0; cf < 4; cf++) {
                int c0 = wn * 64 + cf * 16 + (l & 15);
                int c4 = c0 >> 2, ce = c0 & 3;
#pragma unroll
                for (int v = 0; v < 4; v++) {
                    int rl = wm * 64 + rfq * 16 + (l >> 4) * 4 + v;
                    Cf[rl * 256 + ((c4 ^ (rl & 7)) << 2) + ce] = acc[rf][cf][v];
                }
            }
        }
        __syncthreads();
#pragma unroll
        for (int rb4 = 0; rb4 < 4; rb4++) {
            float4 rz[4], cv[4];
#pragma unroll
            for (int k = 0; k < 4; k++) {
                int rr = (rb4 * 4 + k) * 8 + w;
                int grow = m0 + (rr & 63) + ((rr >> 6) << 7) + pass * 64;
                rz[k] = *(const float4*)(resid + (size_t)grow * 1024 + gcol);
            }
#pragma unroll
            for (int k = 0; k < 4; k++) {
                int rr = (rb4 * 4 + k) * 8 + w;
                cv[k] = *(const float4*)&Cf[rr * 256 + ((l ^ (rr & 7)) << 2)];
            }
#pragma unroll
            for (int k = 0; k < 4; k++) {
                int rr = (rb4 * 4 + k) * 8 + w;
                int grow = m0 + (rr & 63) + ((rr >> 6) << 7) + pass * 64;
                float4 o;
                o.x = cv[k].x + bzv.x + rz[k].x;
                o.y = cv[k].y + bzv.y + rz[k].y;
                o.z = cv[k].z + bzv.z + rz[k].z;
                o.w = cv[k].w + bzv.w + rz[k].w;
                *(float4*)(out + (size_t)grow * 1024 + gcol) = o;
            }
        }
    }
}

// ---------------------------------------------------------------- launch
extern "C" void kernel_launch(void* const* d_in, const int* in_sizes, int n_in,
                              void* d_out, int out_size, void* d_ws, size_t ws_size,
                              hipStream_t stream)
{
    const float* x  = (const float*)d_in[0];
    const float* lg = (const float*)d_in[1];
    const float* lb = (const float*)d_in[2];
    const float* wq = (const float*)d_in[3];
    const float* bq = (const float*)d_in[4];
    const float* wk = (const float*)d_in[5];
    const float* bk = (const float*)d_in[6];
    const float* wv = (const float*)d_in[7];
    const float* bv = (const float*)d_in[8];
    const float* wo = (const float*)d_in[9];
    const float* bo = (const float*)d_in[10];
    const float* rb = (const float*)d_in[11];
    float* out = (float*)d_out;
    unsigned short* ws = (unsigned short*)d_ws;

    unsigned short* wcatT = ws;                        // 3072*1024
    unsigned short* woT   = wcatT + 3145728;           // 1024*1024
    unsigned short* xn    = woT + 1048576;             // 65536*1024
    unsigned short* ctx   = xn + 67108864ull;          // 65536*1024 (separate: fqa races in-place)

    transpose_w<<<dim3(1024), dim3(256), 0, stream>>>(wq, wk, wv, wo, wcatT, woT);
    ln_kernel<<<dim3(16384), dim3(256), 0, stream>>>(x, lg, lb, xn);

    // Fused QKV-GEMM + attention: 256 m-panels x 16 heads.
    fqa_kernel<<<dim3(4096), dim3(512), 0, stream>>>(xn, wcatT, bq, bk, bv, rb, ctx);

    gemm8res<<<dim3(1024), dim3(512), 0, stream>>>(ctx, woT, bo, x, out, 4);
}

// Round 8
// 777.816 us; speedup vs baseline: 1.4741x; 1.0055x over previous
//
#include <hip/hip_runtime.h>
#include <stdint.h>

// B=2048, S=32, D=1024, H=16, DK=64. d_in/d_out FLOAT32; internal bf16.
// Pipeline: transpose_w -> ln -> fqa2 (QKV-GEMM + attention fused) -> gemm8res.
// fqa2: BM=128 (4 batches) x BN=192 (Q|K|V of one head), BK=64, 4 waves,
//       8-phase counted-vmcnt loop, 80 KiB LDS -> 2 blocks/CU, in-LDS attention.

typedef __attribute__((ext_vector_type(8))) short bf16x8;
typedef __attribute__((ext_vector_type(4))) float f32x4;
typedef __attribute__((ext_vector_type(16))) float f32x16;

__device__ __forceinline__ float bf2f(unsigned short u) {
    return __uint_as_float(((unsigned)u) << 16);
}
__device__ __forceinline__ unsigned short f2bf(float f) {
    unsigned u = __float_as_uint(f);
    u += 0x7FFFu + ((u >> 16) & 1u);
    return (unsigned short)(u >> 16);
}
__device__ __forceinline__ uint4 pack8(const float* f) {
    uint4 u;
    u.x = (unsigned)f2bf(f[0]) | ((unsigned)f2bf(f[1]) << 16);
    u.y = (unsigned)f2bf(f[2]) | ((unsigned)f2bf(f[3]) << 16);
    u.z = (unsigned)f2bf(f[4]) | ((unsigned)f2bf(f[5]) << 16);
    u.w = (unsigned)f2bf(f[6]) | ((unsigned)f2bf(f[7]) << 16);
    return u;
}

typedef __attribute__((address_space(3))) unsigned lds_u32;
typedef const __attribute__((address_space(1))) unsigned glb_u32;
__device__ __forceinline__ void gld16(const void* g, void* l) {
    __builtin_amdgcn_global_load_lds((glb_u32*)g, (lds_u32*)l, 16, 0, 0);
}

// ---------------------------------------------------------------- transpose
__global__ __launch_bounds__(256) void transpose_w(
    const float* __restrict__ wq, const float* __restrict__ wk,
    const float* __restrict__ wv, const float* __restrict__ wo,
    unsigned short* __restrict__ wcatT, unsigned short* __restrict__ woT)
{
    __shared__ unsigned short T[64 * 72];
    int bid = blockIdx.x;
    int p = bid >> 8;
    int t = bid & 255;
    int k0 = (t >> 4) * 64, n0 = (t & 15) * 64;
    const float* src = (p == 0) ? wq : (p == 1) ? wk : (p == 2) ? wv : wo;
    unsigned short* dst = (p < 3) ? (wcatT + (size_t)p * 1048576) : woT;
    int tid = threadIdx.x;
#pragma unroll
    for (int it = 0; it < 2; it++) {
        int flat = it * 2048 + tid * 8;
        int r = flat >> 6, c = flat & 63;
        const float* s4 = src + (size_t)(k0 + r) * 1024 + n0 + c;
        float4 u0 = *(const float4*)s4;
        float4 u1 = *(const float4*)(s4 + 4);
        float f[8] = {u0.x, u0.y, u0.z, u0.w, u1.x, u1.y, u1.z, u1.w};
        *(uint4*)&T[r * 72 + c] = pack8(f);
    }
    __syncthreads();
#pragma unroll
    for (int it = 0; it < 2; it++) {
        int flat = it * 2048 + tid * 8;
        int rn = flat >> 6, ck = flat & 63;
        unsigned short v[8];
#pragma unroll
        for (int j = 0; j < 8; j++) v[j] = T[(ck + j) * 72 + rn];
        uint4 u;
        u.x = (unsigned)v[0] | ((unsigned)v[1] << 16);
        u.y = (unsigned)v[2] | ((unsigned)v[3] << 16);
        u.z = (unsigned)v[4] | ((unsigned)v[5] << 16);
        u.w = (unsigned)v[6] | ((unsigned)v[7] << 16);
        *(uint4*)(dst + (size_t)(n0 + rn) * 1024 + k0 + ck) = u;
    }
}

// ---------------------------------------------------------------- layernorm
__global__ __launch_bounds__(256) void ln_kernel(
    const float* __restrict__ x, const float* __restrict__ gg,
    const float* __restrict__ bb, unsigned short* __restrict__ xn)
{
    int l = threadIdx.x & 63;
    size_t row = (size_t)blockIdx.x * 4 + (threadIdx.x >> 6);
    const float* xr = x + row * 1024;
    float f0[8], f1[8];
    *(float4*)&f0[0] = *(const float4*)(xr + l * 8);
    *(float4*)&f0[4] = *(const float4*)(xr + l * 8 + 4);
    *(float4*)&f1[0] = *(const float4*)(xr + 512 + l * 8);
    *(float4*)&f1[4] = *(const float4*)(xr + 512 + l * 8 + 4);
    float s = 0.f, s2 = 0.f;
#pragma unroll
    for (int j = 0; j < 8; j++) { s += f0[j] + f1[j]; s2 += f0[j] * f0[j] + f1[j] * f1[j]; }
#pragma unroll
    for (int m = 1; m < 64; m <<= 1) { s += __shfl_xor(s, m); s2 += __shfl_xor(s2, m); }
    float mu = s * (1.f / 1024.f);
    float var = s2 * (1.f / 1024.f) - mu * mu;
    float rs = rsqrtf(var + 1e-5f);
    float fg0[8], fg1[8], fb0[8], fb1[8];
    *(float4*)&fg0[0] = *(const float4*)(gg + l * 8);
    *(float4*)&fg0[4] = *(const float4*)(gg + l * 8 + 4);
    *(float4*)&fg1[0] = *(const float4*)(gg + 512 + l * 8);
    *(float4*)&fg1[4] = *(const float4*)(gg + 512 + l * 8 + 4);
    *(float4*)&fb0[0] = *(const float4*)(bb + l * 8);
    *(float4*)&fb0[4] = *(const float4*)(bb + l * 8 + 4);
    *(float4*)&fb1[0] = *(const float4*)(bb + 512 + l * 8);
    *(float4*)&fb1[4] = *(const float4*)(bb + 512 + l * 8 + 4);
    float o0[8], o1[8];
#pragma unroll
    for (int j = 0; j < 8; j++) {
        o0[j] = (f0[j] - mu) * rs * fg0[j] + fb0[j];
        o1[j] = (f1[j] - mu) * rs * fg1[j] + fb1[j];
    }
    *(uint4*)(xn + row * 1024 + l * 8) = pack8(o0);
    *(uint4*)(xn + row * 1024 + 512 + l * 8) = pack8(o1);
}

// ---------------------------------------------------------------- common asm helpers
#define FENCE asm volatile("" ::: "memory")
#define BARRIER do { FENCE; __builtin_amdgcn_s_barrier(); FENCE; } while (0)
#define WAIT_LGKM0 do { asm volatile("s_waitcnt lgkmcnt(0)" ::: "memory"); \
                        __builtin_amdgcn_sched_barrier(0); } while (0)
#define VMCNT(n) asm volatile("s_waitcnt vmcnt(" #n ")" ::: "memory")

// ================================================================ fqa2
// Block: 128 A-rows (4 batches) x 1 head, 256 threads = 4 waves (2M x 2N).
// Loop LDS: A dbuf 2x[128][64] (16384 elems), B dbuf 2x[192][64] (24576 elems)
//           = 40960 ushort = 80 KiB -> 2 blocks/CU.
// Attn LDS reuse: Q[128][72] | K[128][72] | VT[4][64][40] | Ps[4][32][40].
#define FQ_SA(buf) (LDSU + (buf) * 8192)
#define FQ_SB(buf) (LDSU + 16384 + (buf) * 12288)
#define QS_OFF 0
#define KS_OFF 9216
#define VT_OFF 18432
#define PS_OFF 28672

// one call stages 32 rows x 64 cols (4 KiB across 4 waves)
#define ASTG(buf, g, koff) gld16(Ag + (size_t)(g) * 32768 + (koff), \
                                 FQ_SA(buf) + ((g) * 32 + w * 8) * 64)
#define BSTG(buf, p, c, koff) gld16(((p) == 0 ? Bgq : (p) == 1 ? Bgk : Bgv) + (size_t)(c) * 32768 + (koff), \
                                    FQ_SB(buf) + ((p) * 64 + (c) * 32 + w * 8) * 64)

#define FLDA(buf, q, ks) (*(const bf16x8*)&FQ_SA(buf)[ \
    (wm * 64 + (q) * 16 + (l & 15)) * 64 + ((((ks) * 32) + khi) ^ aswz)])
#define FLDB(buf, cf, ks) (*(const bf16x8*)&FQ_SB(buf)[ \
    (wn * 96 + (cf) * 16 + (l & 15)) * 64 + ((((ks) * 32) + khi) ^ aswz)])

#define MFMA_HEX(q) do { \
    _Pragma("unroll") \
    for (int cf = 0; cf < 6; cf++) { \
        acc[q][cf] = __builtin_amdgcn_mfma_f32_16x16x32_bf16(aF0, bF[cf][0], acc[q][cf], 0, 0, 0); \
        acc[q][cf] = __builtin_amdgcn_mfma_f32_16x16x32_bf16(aF1, bF[cf][1], acc[q][cf], 0, 0, 0); \
    } } while (0)

#define FPHASE(buf, q, STAGE_STMT, TAIL_STMT) do { \
    bf16x8 aF0 = FLDA(buf, q, 0), aF1 = FLDA(buf, q, 1); \
    if ((q) == 0) { \
        _Pragma("unroll") \
        for (int cf = 0; cf < 6; cf++) { bF[cf][0] = FLDB(buf, cf, 0); bF[cf][1] = FLDB(buf, cf, 1); } \
    } \
    STAGE_STMT; \
    BARRIER; \
    WAIT_LGKM0; \
    __builtin_amdgcn_s_setprio(1); \
    MFMA_HEX(q); \
    __builtin_amdgcn_s_setprio(0); \
    TAIL_STMT; \
    BARRIER; \
} while (0)

__global__ __launch_bounds__(256, 2) void fqa2_kernel(
    const unsigned short* __restrict__ A, const unsigned short* __restrict__ wcatT,
    const float* __restrict__ bq, const float* __restrict__ bk,
    const float* __restrict__ bv, const float* __restrict__ rb,
    unsigned short* __restrict__ ctx)
{
    __shared__ __align__(16) unsigned short LDSU[40960];  // 80 KiB
    int cpx = gridDim.x >> 3;                              // 1024
    int bid = (blockIdx.x & 7) * cpx + (blockIdx.x >> 3);  // 16 head-blocks/panel -> same XCD
    int mp = bid >> 4, h = bid & 15;
    int m0 = mp * 128;
    int tid = threadIdx.x, l = tid & 63, w = tid >> 6;
    int wm = w >> 1, wn = w & 1;
    int khi = (l >> 4) * 8;
    int aswz = (l & 7) * 8;
    int swzc = ((l & 7) ^ (l >> 3)) * 8;

    const unsigned short* Ag  = A + (size_t)(m0 + w * 8 + (l >> 3)) * 1024 + swzc;
    const unsigned short* Bgq = wcatT + (size_t)(h * 64 + w * 8 + (l >> 3)) * 1024 + swzc;
    const unsigned short* Bgk = Bgq + 1048576ull;
    const unsigned short* Bgv = Bgq + 2097152ull;

    f32x4 acc[4][6];
#pragma unroll
    for (int i = 0; i < 4; i++)
#pragma unroll
        for (int j = 0; j < 6; j++)
#pragma unroll
            for (int v = 0; v < 4; v++) acc[i][j][v] = 0.f;

    bf16x8 bF[6][2];

    // Prologue: A(0),B(0) -> buf0; B(1) -> buf1.
    ASTG(0, 0, 0); ASTG(0, 1, 0); ASTG(0, 2, 0); ASTG(0, 3, 0);
    BSTG(0, 0, 0, 0); BSTG(0, 0, 1, 0); BSTG(0, 1, 0, 0);
    BSTG(0, 1, 1, 0); BSTG(0, 2, 0, 0); BSTG(0, 2, 1, 0);
    BSTG(1, 0, 0, 64); BSTG(1, 0, 1, 64); BSTG(1, 1, 0, 64);
    BSTG(1, 1, 1, 64); BSTG(1, 2, 0, 64); BSTG(1, 2, 1, 64);
    VMCNT(6);
    BARRIER;

    for (int it = 0; it < 7; ++it) {
        int ko1 = (2 * it + 1) * 64, ko2 = (2 * it + 2) * 64, ko3 = (2 * it + 3) * 64;
        FPHASE(0, 0, do { ASTG(1, 0, ko1); ASTG(1, 1, ko1); } while (0), (void)0);
        FPHASE(0, 1, do { ASTG(1, 2, ko1); ASTG(1, 3, ko1); } while (0), (void)0);
        FPHASE(0, 2, do { BSTG(0, 0, 0, ko2); BSTG(0, 0, 1, ko2); BSTG(0, 1, 0, ko2); } while (0), (void)0);
        FPHASE(0, 3, do { BSTG(0, 1, 1, ko2); BSTG(0, 2, 0, ko2); BSTG(0, 2, 1, ko2); } while (0), VMCNT(6));
        FPHASE(1, 0, do { ASTG(0, 0, ko2); ASTG(0, 1, ko2); } while (0), (void)0);
        FPHASE(1, 1, do { ASTG(0, 2, ko2); ASTG(0, 3, ko2); } while (0), (void)0);
        FPHASE(1, 2, do { BSTG(1, 0, 0, ko3); BSTG(1, 0, 1, ko3); BSTG(1, 1, 0, ko3); } while (0), (void)0);
        FPHASE(1, 3, do { BSTG(1, 1, 1, ko3); BSTG(1, 2, 0, ko3); BSTG(1, 2, 1, ko3); } while (0), VMCNT(6));
    }
    // Final tiles 14 (buf0), 15 (buf1): only A(15) left to stage.
    FPHASE(0, 0, do { ASTG(1, 0, 960); ASTG(1, 1, 960); } while (0), (void)0);
    FPHASE(0, 1, do { ASTG(1, 2, 960); ASTG(1, 3, 960); } while (0), (void)0);
    FPHASE(0, 2, (void)0, (void)0);
    FPHASE(0, 3, (void)0, VMCNT(0));
    FPHASE(1, 0, (void)0, (void)0);
    FPHASE(1, 1, (void)0, (void)0);
    FPHASE(1, 2, (void)0, (void)0);
    FPHASE(1, 3, (void)0, (void)0);
    __builtin_amdgcn_sched_barrier(0);

    // ---- repack acc -> LDS: Q[128][72], K[128][72], VT[4][64][40] (bias fused)
    // col = wn*96 + cf*16 + (l&15). Segment map (wave-uniform per cf):
    //  wn=0: cf0-3 -> Q[0..63], cf4-5 -> K[0..31]
    //  wn=1: cf0-1 -> K[32..63], cf2-5 -> V[0..63]
#pragma unroll
    for (int cf = 0; cf < 6; cf++) {
        int colg = wn * 96 + cf * 16 + (l & 15);
        int seg = colg >> 6;                  // wave-uniform: 0=Q,1=K,2=V
        int cseg = colg & 63;
        const float* bp = (seg == 0) ? bq : (seg == 1) ? bk : bv;
        float bias = bp[h * 64 + cseg];
#pragma unroll
        for (int ai = 0; ai < 4; ai++) {
#pragma unroll
            for (int v = 0; v < 4; v++) {
                int row = wm * 64 + ai * 16 + (l >> 4) * 4 + v;  // b*32+s (0..127)
                unsigned short val = f2bf(acc[ai][cf][v] + bias);
                if (seg == 0)      LDSU[QS_OFF + row * 72 + cseg] = val;
                else if (seg == 1) LDSU[KS_OFF + row * 72 + cseg] = val;
                else               LDSU[VT_OFF + (((row >> 5) << 6) + cseg) * 40 + (row & 31)] = val;
            }
        }
    }
    __syncthreads();

    // ---- in-LDS attention: wave w handles batch b=w (rows w*32..w*32+31)
    {
        int col = l & 31, hi = l >> 5;
        f32x16 s;
#pragma unroll
        for (int i = 0; i < 16; i++) s[i] = 0.f;
#pragma unroll
        for (int t = 0; t < 4; t++) {
            bf16x8 aQ = *(const bf16x8*)&LDSU[QS_OFF + (w * 32 + col) * 72 + t * 16 + hi * 8];
            bf16x8 bK = *(const bf16x8*)&LDSU[KS_OFF + (w * 32 + col) * 72 + t * 16 + hi * 8];
            s = __builtin_amdgcn_mfma_f32_32x32x16_bf16(aQ, bK, s, 0, 0, 0);
        }
        const float* rbh = rb + h * 1024;
        unsigned short* ps = LDSU + PS_OFF + w * 1280;
#pragma unroll
        for (int r = 0; r < 16; r++) {
            int m = (r & 3) + 8 * (r >> 2) + 4 * hi;
            float v = s[r] * 0.125f + rbh[m * 32 + col];
            float mx = v;
#pragma unroll
            for (int msk = 1; msk < 32; msk <<= 1) mx = fmaxf(mx, __shfl_xor(mx, msk));
            float e = __expf(v - mx);
            float sm = e;
#pragma unroll
            for (int msk = 1; msk < 32; msk <<= 1) sm += __shfl_xor(sm, msk);
            ps[m * 40 + col] = f2bf(e / sm);
        }
        bf16x8 pa0 = *(const bf16x8*)&ps[col * 40 + hi * 8];
        bf16x8 pa1 = *(const bf16x8*)&ps[col * 40 + 16 + hi * 8];
        size_t rowb = ((size_t)mp * 4 + w) * 32;
#pragma unroll
        for (int c2 = 0; c2 < 2; c2++) {
            bf16x8 vb0 = *(const bf16x8*)&LDSU[VT_OFF + (w * 64 + c2 * 32 + col) * 40 + hi * 8];
            bf16x8 vb1 = *(const bf16x8*)&LDSU[VT_OFF + (w * 64 + c2 * 32 + col) * 40 + 16 + hi * 8];
            f32x16 o;
#pragma unroll
            for (int i = 0; i < 16; i++) o[i] = 0.f;
            o = __builtin_amdgcn_mfma_f32_32x32x16_bf16(pa0, vb0, o, 0, 0, 0);
            o = __builtin_amdgcn_mfma_f32_32x32x16_bf16(pa1, vb1, o, 0, 0, 0);
#pragma unroll
            for (int r = 0; r < 16; r++) {
                int m = (r & 3) + 8 * (r >> 2) + 4 * hi;
                ctx[(rowb + m) * 1024 + h * 64 + c2 * 32 + col] = f2bf(o[r]);
            }
        }
    }
}

// ================================================================ gemm8res (output proj + residual)
#define SAp(buf) (LDSB + (buf) * 16384)
#define SBp(buf) (LDSB + 32768 + (buf) * 16384)

#define STG(gb, hh, kcol, ldsreg) do { \
    const unsigned short* _g = (gb) + (size_t)((hh) * 128) * 1024 + (kcol); \
    unsigned short* _d = (ldsreg) + ((hh) * 128 + w * 8) * 64; \
    gld16(_g, _d); gld16(_g + 64 * 1024, _d + 64 * 64); } while (0)

#define LDA(buf, q, rfq, ks) (*(const bf16x8*)&SAp(buf)[ \
    (wm * 128 + (q) * 32 + (rfq) * 16 + (l & 15)) * 64 + ((((ks) * 32) + khi) ^ aswz)])
#define LDB(buf, cf, ks) (*(const bf16x8*)&SBp(buf)[ \
    (wn * 64 + (cf) * 16 + (l & 15)) * 64 + ((((ks) * 32) + khi) ^ aswz)])

#define MFMA_QUAD(q) do { \
    _Pragma("unroll") \
    for (int cf = 0; cf < 4; cf++) { \
        acc[(q)*2+0][cf] = __builtin_amdgcn_mfma_f32_16x16x32_bf16(aF00, bF[cf][0], acc[(q)*2+0][cf], 0, 0, 0); \
        acc[(q)*2+0][cf] = __builtin_amdgcn_mfma_f32_16x16x32_bf16(aF01, bF[cf][1], acc[(q)*2+0][cf], 0, 0, 0); \
        acc[(q)*2+1][cf] = __builtin_amdgcn_mfma_f32_16x16x32_bf16(aF10, bF[cf][0], acc[(q)*2+1][cf], 0, 0, 0); \
        acc[(q)*2+1][cf] = __builtin_amdgcn_mfma_f32_16x16x32_bf16(aF11, bF[cf][1], acc[(q)*2+1][cf], 0, 0, 0); \
    } } while (0)

#define PHASE(buf, q, STAGE_STMT, TAIL_STMT) do { \
    bf16x8 aF00 = LDA(buf, q, 0, 0), aF01 = LDA(buf, q, 0, 1); \
    bf16x8 aF10 = LDA(buf, q, 1, 0), aF11 = LDA(buf, q, 1, 1); \
    if ((q) == 0) { \
        _Pragma("unroll") \
        for (int cf = 0; cf < 4; cf++) { bF[cf][0] = LDB(buf, cf, 0); bF[cf][1] = LDB(buf, cf, 1); } \
    } \
    STAGE_STMT; \
    BARRIER; \
    WAIT_LGKM0; \
    __builtin_amdgcn_s_setprio(1); \
    MFMA_QUAD(q); \
    __builtin_amdgcn_s_setprio(0); \
    TAIL_STMT; \
    BARRIER; \
} while (0)

__global__ __launch_bounds__(512, 2) void gemm8res(
    const unsigned short* __restrict__ A, const unsigned short* __restrict__ Bt,
    const float* __restrict__ bz0, const float* __restrict__ resid,
    float* __restrict__ out, int NTL)
{
    __shared__ __align__(16) unsigned short LDSB[65536];  // 128 KiB
    int cpx = gridDim.x >> 3;
    int bid = (blockIdx.x & 7) * cpx + (blockIdx.x >> 3);
    int mt = bid / NTL, ntl = bid % NTL;
    int m0 = mt * 256, n0 = ntl * 256;
    int tid = threadIdx.x, l = tid & 63, w = tid >> 6;
    int wm = w >> 2, wn = w & 3;
    int khi = (l >> 4) * 8;
    int aswz = (l & 7) * 8;

    const unsigned short* Ag = A + (size_t)(m0 + w * 8 + (l >> 3)) * 1024 + ((l & 7) ^ (l >> 3)) * 8;
    const unsigned short* Bg = Bt + (size_t)(n0 + w * 8 + (l >> 3)) * 1024 + ((l & 7) ^ (l >> 3)) * 8;
    unsigned short* sA0 = SAp(0);
    unsigned short* sA1 = SAp(1);
    unsigned short* sB0 = SBp(0);
    unsigned short* sB1 = SBp(1);

    f32x4 acc[8][4];
#pragma unroll
    for (int i = 0; i < 8; i++)
#pragma unroll
        for (int j = 0; j < 4; j++)
#pragma unroll
            for (int v = 0; v < 4; v++) acc[i][j][v] = 0.f;

    bf16x8 bF[4][2];

    STG(Ag, 0, 0, sA0); STG(Ag, 1, 0, sA0);
    STG(Bg, 0, 0, sB0); STG(Bg, 1, 0, sB0);
    STG(Bg, 0, 64, sB1); STG(Bg, 1, 64, sB1);
    VMCNT(4);
    BARRIER;

    for (int it = 0; it < 7; ++it) {
        int koff = it * 128;
        PHASE(0, 0, STG(Ag, 0, koff + 64, sA1), (void)0);
        PHASE(0, 1, STG(Ag, 1, koff + 64, sA1), (void)0);
        PHASE(0, 2, STG(Bg, 0, koff + 128, sB0), (void)0);
        PHASE(0, 3, STG(Bg, 1, koff + 128, sB0), VMCNT(4));
        PHASE(1, 0, STG(Ag, 0, koff + 128, sA0), (void)0);
        PHASE(1, 1, STG(Ag, 1, koff + 128, sA0), (void)0);
        PHASE(1, 2, STG(Bg, 0, koff + 192, sB1), (void)0);
        PHASE(1, 3, STG(Bg, 1, koff + 192, sB1), VMCNT(4));
    }
    PHASE(0, 0, STG(Ag, 0, 960, sA1), (void)0);
    PHASE(0, 1, STG(Ag, 1, 960, sA1), (void)0);
    PHASE(0, 2, (void)0, (void)0);
    PHASE(0, 3, (void)0, VMCNT(0));
    PHASE(1, 0, (void)0, (void)0);
    PHASE(1, 1, (void)0, (void)0);
    PHASE(1, 2, (void)0, (void)0);
    PHASE(1, 3, (void)0, (void)0);
    __builtin_amdgcn_sched_barrier(0);

    // LDS-repack f32 epilogue: + bias + residual, coalesced float4 I/O.
    float* Cf = (float*)LDSB;
    int gcol = n0 + l * 4;
    float4 bzv = *(const float4*)(bz0 + gcol);
#pragma unroll
    for (int pass = 0; pass < 2; pass++) {
        __syncthreads();
#pragma unroll
        for (int rfq = 0; rfq < 4; rfq++) {
            int rf = pass * 4 + rfq;
#pragma unroll
            for (int cf = 0; cf < 4; cf++) {
                int c0 = wn * 64 + cf * 16 + (l & 15);
                int c4 = c0 >> 2, ce = c0 & 3;
#pragma unroll
                for (int v = 0; v < 4; v++) {
                    int rl = wm * 64 + rfq * 16 + (l >> 4) * 4 + v;
                    Cf[rl * 256 + ((c4 ^ (rl & 7)) << 2) + ce] = acc[rf][cf][v];
                }
            }
        }
        __syncthreads();
#pragma unroll
        for (int rb4 = 0; rb4 < 4; rb4++) {
            float4 rz[4], cv[4];
#pragma unroll
            for (int k = 0; k < 4; k++) {
                int rr = (rb4 * 4 + k) * 8 + w;
                int grow = m0 + (rr & 63) + ((rr >> 6) << 7) + pass * 64;
                rz[k] = *(const float4*)(resid + (size_t)grow * 1024 + gcol);
            }
#pragma unroll
            for (int k = 0; k < 4; k++) {
                int rr = (rb4 * 4 + k) * 8 + w;
                cv[k] = *(const float4*)&Cf[rr * 256 + ((l ^ (rr & 7)) << 2)];
            }
#pragma unroll
            for (int k = 0; k < 4; k++) {
                int rr = (rb4 * 4 + k) * 8 + w;
                int grow = m0 + (rr & 63) + ((rr >> 6) << 7) + pass * 64;
                float4 o;
                o.x = cv[k].x + bzv.x + rz[k].x;
                o.y = cv[k].y + bzv.y + rz[k].y;
                o.z = cv[k].z + bzv.z + rz[k].z;
                o.w = cv[k].w + bzv.w + rz[k].w;
                *(float4*)(out + (size_t)grow * 1024 + gcol) = o;
            }
        }
    }
}

// ---------------------------------------------------------------- launch
extern "C" void kernel_launch(void* const* d_in, const int* in_sizes, int n_in,
                              void* d_out, int out_size, void* d_ws, size_t ws_size,
                              hipStream_t stream)
{
    const float* x  = (const float*)d_in[0];
    const float* lg = (const float*)d_in[1];
    const float* lb = (const float*)d_in[2];
    const float* wq = (const float*)d_in[3];
    const float* bq = (const float*)d_in[4];
    const float* wk = (const float*)d_in[5];
    const float* bk = (const float*)d_in[6];
    const float* wv = (const float*)d_in[7];
    const float* bv = (const float*)d_in[8];
    const float* wo = (const float*)d_in[9];
    const float* bo = (const float*)d_in[10];
    const float* rb = (const float*)d_in[11];
    float* out = (float*)d_out;
    unsigned short* ws = (unsigned short*)d_ws;

    unsigned short* wcatT = ws;                        // 3072*1024
    unsigned short* woT   = wcatT + 3145728;           // 1024*1024
    unsigned short* xn    = woT + 1048576;             // 65536*1024
    unsigned short* ctx   = xn + 67108864ull;          // 65536*1024

    transpose_w<<<dim3(1024), dim3(256), 0, stream>>>(wq, wk, wv, wo, wcatT, woT);
    ln_kernel<<<dim3(16384), dim3(256), 0, stream>>>(x, lg, lb, xn);

    // Fused QKV-GEMM + attention: 512 m-panels x 16 heads, 2 blocks/CU.
    fqa2_kernel<<<dim3(8192), dim3(256), 0, stream>>>(xn, wcatT, bq, bk, bv, rb, ctx);

    gemm8res<<<dim3(1024), dim3(512), 0, stream>>>(ctx, woT, bo, x, out, 4);
}